// Round 3
// baseline (5008.075 us; speedup 1.0000x reference)
//
#include <hip/hip_runtime.h>
#include <hip/hip_bf16.h>
#include <math.h>

typedef __bf16 bf16_t;
typedef bf16_t bf16x8 __attribute__((ext_vector_type(8)));
typedef float f32x4 __attribute__((ext_vector_type(4)));
typedef unsigned short u16;

static __device__ __forceinline__ u16 f2bf(float f) {
    unsigned u = __builtin_bit_cast(unsigned, f);
    u += 0x7FFFu + ((u >> 16) & 1u);
    return (u16)(u >> 16);
}
static __device__ __forceinline__ float bf2f(u16 v) {
    unsigned u = (unsigned)v << 16;
    return __builtin_bit_cast(float, u);
}

// ---------------- LayerNorm: fp32 in -> bf16 out, one block per row (D=1024) --
__global__ __launch_bounds__(256) void ln_kernel(
    const float* __restrict__ x, const float* __restrict__ g,
    const float* __restrict__ be, u16* __restrict__ out)
{
    const int row = blockIdx.x;
    const int tid = threadIdx.x;
    const float4 v = ((const float4*)(x + (long)row * 1024))[tid];
    float s = v.x + v.y + v.z + v.w;
#pragma unroll
    for (int d = 32; d >= 1; d >>= 1) s += __shfl_xor(s, d);
    __shared__ float r1[4], r2[4];
    if ((tid & 63) == 0) r1[tid >> 6] = s;
    __syncthreads();
    const float mean = (r1[0] + r1[1] + r1[2] + r1[3]) * (1.0f / 1024.0f);
    const float dx = v.x - mean, dy = v.y - mean, dz = v.z - mean, dw = v.w - mean;
    float sq = dx * dx + dy * dy + dz * dz + dw * dw;
#pragma unroll
    for (int d = 32; d >= 1; d >>= 1) sq += __shfl_xor(sq, d);
    if ((tid & 63) == 0) r2[tid >> 6] = sq;
    __syncthreads();
    const float var = (r2[0] + r2[1] + r2[2] + r2[3]) * (1.0f / 1024.0f);
    const float rstd = rsqrtf(var + 1e-5f);
    const float4 gg = ((const float4*)g)[tid];
    const float4 bb = ((const float4*)be)[tid];
    ushort4 o;
    o.x = f2bf(dx * rstd * gg.x + bb.x);
    o.y = f2bf(dy * rstd * gg.y + bb.y);
    o.z = f2bf(dz * rstd * gg.z + bb.z);
    o.w = f2bf(dw * rstd * gg.w + bb.w);
    *(ushort4*)&out[(long)row * 1024 + tid * 4] = o;
}

// ---------------- Transpose + cvt: fp32 [R][C] -> bf16 [C][R] ----------------
__global__ __launch_bounds__(256) void tcvt_kernel(
    const float* __restrict__ in, u16* __restrict__ outT, int R, int C)
{
    __shared__ float tile[32][33];
    const int tx = threadIdx.x, ty = threadIdx.y; // 32 x 8
    const int c0 = blockIdx.x * 32, r0 = blockIdx.y * 32;
#pragma unroll
    for (int i = 0; i < 4; ++i)
        tile[ty + i * 8][tx] = in[(long)(r0 + ty + i * 8) * C + c0 + tx];
    __syncthreads();
#pragma unroll
    for (int i = 0; i < 4; ++i)
        outT[(long)(c0 + ty + i * 8) * R + r0 + tx] = f2bf(tile[tx][ty + i * 8]);
}

// ---------------- GEMM: C[M,N] = A[M,K] @ Bt[N,K]^T + bias, m97 structure ----
// EPI 0: store bf16. EPI 1: exact GELU -> bf16. EPI 2: += fp32 residual -> fp32.
template <int EPI>
__global__ __launch_bounds__(256) void gemm_bt(
    const u16* __restrict__ A, const u16* __restrict__ Bt,
    const float* __restrict__ bias, const float* __restrict__ resid,
    void* __restrict__ C, int M, int N, int K)
{
    __shared__ __align__(16) u16 As[128 * 32];
    __shared__ __align__(16) u16 Bs[128 * 32];
    const int tid = threadIdx.x;
    const int lane = tid & 63;
    const int w = tid >> 6;
    const int wm = w >> 1, wn = w & 1;
    const int bm = blockIdx.x, bn = blockIdx.y;
    f32x4 acc[4][4] = {};

    const u16* Ablk = A + (long)bm * 128 * K;
    const u16* Bblk = Bt + (long)bn * 128 * K;

    for (int kb = 0; kb < K; kb += 32) {
        __syncthreads();
#pragma unroll
        for (int i = 0; i < 2; ++i) {
            const int o = (w * 2 + i) * 512 + lane * 8;
            const int row = o >> 5, kk = o & 31;
            const u16* ga = Ablk + (long)row * K + kb + kk;
            const u16* gb = Bblk + (long)row * K + kb + kk;
            __builtin_amdgcn_global_load_lds(
                (const __attribute__((address_space(1))) void*)ga,
                (__attribute__((address_space(3))) void*)(As + (w * 2 + i) * 512),
                16, 0, 0);
            __builtin_amdgcn_global_load_lds(
                (const __attribute__((address_space(1))) void*)gb,
                (__attribute__((address_space(3))) void*)(Bs + (w * 2 + i) * 512),
                16, 0, 0);
        }
        __syncthreads();
        bf16x8 af[4], bfr[4];
#pragma unroll
        for (int m = 0; m < 4; ++m)
            af[m] = *(const bf16x8*)&As[(wm * 64 + m * 16 + (lane & 15)) * 32 + (lane >> 4) * 8];
#pragma unroll
        for (int n = 0; n < 4; ++n)
            bfr[n] = *(const bf16x8*)&Bs[(wn * 64 + n * 16 + (lane & 15)) * 32 + (lane >> 4) * 8];
#pragma unroll
        for (int m = 0; m < 4; ++m)
#pragma unroll
            for (int n = 0; n < 4; ++n)
                acc[m][n] = __builtin_amdgcn_mfma_f32_16x16x32_bf16(af[m], bfr[n], acc[m][n], 0, 0, 0);
    }

    const int rowBase = bm * 128 + wm * 64;
    const int colBase = bn * 128 + wn * 64;
#pragma unroll
    for (int n = 0; n < 4; ++n) {
        const int col = colBase + n * 16 + (lane & 15);
        const float bv = bias[col];
#pragma unroll
        for (int m = 0; m < 4; ++m) {
#pragma unroll
            for (int r = 0; r < 4; ++r) {
                const int row = rowBase + m * 16 + (lane >> 4) * 4 + r;
                float v = acc[m][n][r] + bv;
                if constexpr (EPI == 1) v = 0.5f * v * (1.0f + erff(v * 0.70710678118654752f));
                if constexpr (EPI == 2) {
                    ((float*)C)[(long)row * N + col] = v + resid[(long)row * N + col];
                } else {
                    ((u16*)C)[(long)row * N + col] = f2bf(v);
                }
            }
        }
    }
}

// ---------------- BISECT: naive causal attention, one wave per query row -----
// qkv: bf16 [B*S][3072] (q|k|v). out: bf16 [B*S][1024], col = h*64 + d.
// Obviously-correct online softmax, fp32 accumulation, lane = head-dim element.
__global__ __launch_bounds__(256) void attn_naive(
    const u16* __restrict__ qkv, u16* __restrict__ outb)
{
    const int S = 2048;
    const int tid = threadIdx.x, lane = tid & 63, w = tid >> 6;
    const int wg = blockIdx.x * 4 + w;       // global wave id, 0..65535
    const int q  = wg & (S - 1);             // query row within (b,h)
    const int bh = wg >> 11;                 // 0..31
    const int b = bh >> 4, h = bh & 15;
    const long base = (long)b * S * 3072;

    const float qd = bf2f(qkv[base + (long)q * 3072 + h * 64 + lane]) * 0.125f;
    const u16* kp = qkv + base + 1024 + h * 64 + lane;
    const u16* vp = qkv + base + 2048 + h * 64 + lane;

    float m = -1e30f, l = 0.0f, o = 0.0f;
    for (int kv = 0; kv <= q; ++kv) {
        float p = qd * bf2f(kp[(long)kv * 3072]);
#pragma unroll
        for (int d = 32; d >= 1; d >>= 1) p += __shfl_xor(p, d);
        const float mn = fmaxf(m, p);
        const float sc = __expf(m - mn);
        const float e  = __expf(p - mn);
        l = l * sc + e;
        o = o * sc + e * bf2f(vp[(long)kv * 3072]);
        m = mn;
    }
    outb[((long)b * S + q) * 1024 + h * 64 + lane] = f2bf(o / l);
}

// -----------------------------------------------------------------------------
// Workspace plan (56 MiB total; x1 lives in d_out):
//   [0        , 6291456 )  wTa   bf16 [3072][1024]   (dead after qkv GEMM)
//   [6291456  , 8388608 )  wTap  bf16 [1024][1024]   (dead after attn-proj)
//   [8388608  , 16777216)  wTfc  bf16 [4096][1024]
//   [16777216 , 25165824)  wTfp  bf16 [1024][4096]
//   [25165824 , 33554432)  hao   bf16 [4096][1024]   h (ln1 out), then ao (attn out)
//   [33554432 , 58720256)  qkv   bf16 [4096][3072]
//   mb = [25165824, 58720256) bf16 [4096][4096]      (over hao∪qkv, both dead)
//   h2 = [0, 8388608)       bf16 [4096][1024]        (over wTa∪wTap, both dead)
extern "C" void kernel_launch(void* const* d_in, const int* in_sizes, int n_in,
                              void* d_out, int out_size, void* d_ws, size_t ws_size,
                              hipStream_t stream) {
    const float* x      = (const float*)d_in[0];
    const float* ln1_g  = (const float*)d_in[1];
    const float* ln1_b  = (const float*)d_in[2];
    const float* w_attn = (const float*)d_in[3];
    const float* b_attn = (const float*)d_in[4];
    const float* w_ap   = (const float*)d_in[5];
    const float* b_ap   = (const float*)d_in[6];
    const float* ln2_g  = (const float*)d_in[7];
    const float* ln2_b  = (const float*)d_in[8];
    const float* w_fc   = (const float*)d_in[9];
    const float* b_fc   = (const float*)d_in[10];
    const float* w_fp   = (const float*)d_in[11];
    const float* b_fp   = (const float*)d_in[12];
    float* out = (float*)d_out;

    const int R = 4096; // B*S
    char* p = (char*)d_ws;
    u16*   wTa  = (u16*)(p);
    u16*   wTap = (u16*)(p + 6291456);
    u16*   wTfc = (u16*)(p + 8388608);
    u16*   wTfp = (u16*)(p + 16777216);
    u16*   hao  = (u16*)(p + 25165824);   // h, later reused as ao
    u16*   qkv  = (u16*)(p + 33554432);
    u16*   mb   = hao;                    // spans hao + qkv (33,554,432 B)
    u16*   h2   = wTa;                    // spans wTa + wTap (8,388,608 B)
    float* x1   = out;                    // residual stream lives in d_out

    const dim3 tb(32, 8);
    tcvt_kernel<<<dim3(3072 / 32, 1024 / 32), tb, 0, stream>>>(w_attn, wTa, 1024, 3072);
    tcvt_kernel<<<dim3(1024 / 32, 1024 / 32), tb, 0, stream>>>(w_ap, wTap, 1024, 1024);
    tcvt_kernel<<<dim3(4096 / 32, 1024 / 32), tb, 0, stream>>>(w_fc, wTfc, 1024, 4096);
    tcvt_kernel<<<dim3(1024 / 32, 4096 / 32), tb, 0, stream>>>(w_fp, wTfp, 4096, 1024);

    ln_kernel<<<R, 256, 0, stream>>>(x, ln1_g, ln1_b, hao);
    gemm_bt<0><<<dim3(32, 24), 256, 0, stream>>>(hao, wTa, b_attn, nullptr, qkv, R, 3072, 1024);
    attn_naive<<<16384, 256, 0, stream>>>(qkv, hao);
    gemm_bt<2><<<dim3(32, 8), 256, 0, stream>>>(hao, wTap, b_ap, x, x1, R, 1024, 1024);
    ln_kernel<<<R, 256, 0, stream>>>(x1, ln2_g, ln2_b, h2);
    gemm_bt<1><<<dim3(32, 32), 256, 0, stream>>>(h2, wTfc, b_fc, nullptr, mb, R, 4096, 1024);
    gemm_bt<2><<<dim3(32, 8), 256, 0, stream>>>(mb, wTfp, b_fp, x1, out, R, 1024, 4096);
}

// Round 4
// 417.558 us; speedup vs baseline: 11.9937x; 11.9937x over previous
//
#include <hip/hip_runtime.h>
#include <hip/hip_bf16.h>
#include <math.h>

typedef __bf16 bf16_t;
typedef bf16_t bf16x8 __attribute__((ext_vector_type(8)));
typedef float f32x4 __attribute__((ext_vector_type(4)));
typedef unsigned short u16;
typedef u16 ushort8 __attribute__((ext_vector_type(8)));

static __device__ __forceinline__ u16 f2bf(float f) {
    unsigned u = __builtin_bit_cast(unsigned, f);
    u += 0x7FFFu + ((u >> 16) & 1u);
    return (u16)(u >> 16);
}

// ---------------- LayerNorm: fp32 in -> bf16 out, one block per row (D=1024) --
__global__ __launch_bounds__(256) void ln_kernel(
    const float* __restrict__ x, const float* __restrict__ g,
    const float* __restrict__ be, u16* __restrict__ out)
{
    const int row = blockIdx.x;
    const int tid = threadIdx.x;
    const float4 v = ((const float4*)(x + (long)row * 1024))[tid];
    float s = v.x + v.y + v.z + v.w;
#pragma unroll
    for (int d = 32; d >= 1; d >>= 1) s += __shfl_xor(s, d);
    __shared__ float r1[4], r2[4];
    if ((tid & 63) == 0) r1[tid >> 6] = s;
    __syncthreads();
    const float mean = (r1[0] + r1[1] + r1[2] + r1[3]) * (1.0f / 1024.0f);
    const float dx = v.x - mean, dy = v.y - mean, dz = v.z - mean, dw = v.w - mean;
    float sq = dx * dx + dy * dy + dz * dz + dw * dw;
#pragma unroll
    for (int d = 32; d >= 1; d >>= 1) sq += __shfl_xor(sq, d);
    if ((tid & 63) == 0) r2[tid >> 6] = sq;
    __syncthreads();
    const float var = (r2[0] + r2[1] + r2[2] + r2[3]) * (1.0f / 1024.0f);
    const float rstd = rsqrtf(var + 1e-5f);
    const float4 gg = ((const float4*)g)[tid];
    const float4 bb = ((const float4*)be)[tid];
    ushort4 o;
    o.x = f2bf(dx * rstd * gg.x + bb.x);
    o.y = f2bf(dy * rstd * gg.y + bb.y);
    o.z = f2bf(dz * rstd * gg.z + bb.z);
    o.w = f2bf(dw * rstd * gg.w + bb.w);
    *(ushort4*)&out[(long)row * 1024 + tid * 4] = o;
}

// ---------------- Transpose + cvt: fp32 [R][C] -> bf16 [C][R] ----------------
__global__ __launch_bounds__(256) void tcvt_kernel(
    const float* __restrict__ in, u16* __restrict__ outT, int R, int C)
{
    __shared__ float tile[32][33];
    const int tx = threadIdx.x, ty = threadIdx.y; // 32 x 8
    const int c0 = blockIdx.x * 32, r0 = blockIdx.y * 32;
#pragma unroll
    for (int i = 0; i < 4; ++i)
        tile[ty + i * 8][tx] = in[(long)(r0 + ty + i * 8) * C + c0 + tx];
    __syncthreads();
#pragma unroll
    for (int i = 0; i < 4; ++i)
        outT[(long)(c0 + ty + i * 8) * R + r0 + tx] = f2bf(tile[tx][ty + i * 8]);
}

// ---------------- GEMM: C[M,N] = A[M,K] @ Bt[N,K]^T + bias, m97 structure ----
// EPI 0: store bf16. EPI 1: exact GELU -> bf16. EPI 2: += fp32 residual -> fp32.
template <int EPI>
__global__ __launch_bounds__(256) void gemm_bt(
    const u16* __restrict__ A, const u16* __restrict__ Bt,
    const float* __restrict__ bias, const float* __restrict__ resid,
    void* __restrict__ C, int M, int N, int K)
{
    __shared__ __align__(16) u16 As[128 * 32];
    __shared__ __align__(16) u16 Bs[128 * 32];
    const int tid = threadIdx.x;
    const int lane = tid & 63;
    const int w = tid >> 6;
    const int wm = w >> 1, wn = w & 1;
    const int bm = blockIdx.x, bn = blockIdx.y;
    f32x4 acc[4][4] = {};

    const u16* Ablk = A + (long)bm * 128 * K;
    const u16* Bblk = Bt + (long)bn * 128 * K;

    for (int kb = 0; kb < K; kb += 32) {
        __syncthreads();
#pragma unroll
        for (int i = 0; i < 2; ++i) {
            const int o = (w * 2 + i) * 512 + lane * 8;
            const int row = o >> 5, kk = o & 31;
            const u16* ga = Ablk + (long)row * K + kb + kk;
            const u16* gb = Bblk + (long)row * K + kb + kk;
            __builtin_amdgcn_global_load_lds(
                (const __attribute__((address_space(1))) void*)ga,
                (__attribute__((address_space(3))) void*)(As + (w * 2 + i) * 512),
                16, 0, 0);
            __builtin_amdgcn_global_load_lds(
                (const __attribute__((address_space(1))) void*)gb,
                (__attribute__((address_space(3))) void*)(Bs + (w * 2 + i) * 512),
                16, 0, 0);
        }
        __syncthreads();
        bf16x8 af[4], bfr[4];
#pragma unroll
        for (int m = 0; m < 4; ++m)
            af[m] = *(const bf16x8*)&As[(wm * 64 + m * 16 + (lane & 15)) * 32 + (lane >> 4) * 8];
#pragma unroll
        for (int n = 0; n < 4; ++n)
            bfr[n] = *(const bf16x8*)&Bs[(wn * 64 + n * 16 + (lane & 15)) * 32 + (lane >> 4) * 8];
#pragma unroll
        for (int m = 0; m < 4; ++m)
#pragma unroll
            for (int n = 0; n < 4; ++n)
                acc[m][n] = __builtin_amdgcn_mfma_f32_16x16x32_bf16(af[m], bfr[n], acc[m][n], 0, 0, 0);
    }

    const int rowBase = bm * 128 + wm * 64;
    const int colBase = bn * 128 + wn * 64;
#pragma unroll
    for (int n = 0; n < 4; ++n) {
        const int col = colBase + n * 16 + (lane & 15);
        const float bv = bias[col];
#pragma unroll
        for (int m = 0; m < 4; ++m) {
#pragma unroll
            for (int r = 0; r < 4; ++r) {
                const int row = rowBase + m * 16 + (lane >> 4) * 4 + r;
                float v = acc[m][n][r] + bv;
                if constexpr (EPI == 1) v = 0.5f * v * (1.0f + erff(v * 0.70710678118654752f));
                if constexpr (EPI == 2) {
                    ((float*)C)[(long)row * N + col] = v + resid[(long)row * N + col];
                } else {
                    ((u16*)C)[(long)row * N + col] = f2bf(v);
                }
            }
        }
    }
}

// ---------------- Flash attention v2 (causal), 64 q-rows/block, 4 waves ------
// qkv: bf16 [B*S][3072] (q|k|v). out: bf16 [B*S][1024], col = h*64 + d.
// No native __bf16 element ops anywhere: pure vector moves + manual f2bf.
// S scaled by 0.125 in fp32 AFTER the MFMA. V^T staged without swizzle.
__global__ __launch_bounds__(256) void attn_kernel(
    const u16* __restrict__ qkv, u16* __restrict__ outb)
{
    const int S = 2048;
    const int qt = blockIdx.x;           // q-tile (64 rows)
    const int bh = blockIdx.y;           // b*16 + h
    const int b = bh >> 4, h = bh & 15;
    const int tid = threadIdx.x, lane = tid & 63, w = tid >> 6;
    const int q0 = qt * 64;
    __shared__ __align__(16) u16 Ks[64 * 72];        // [kv][hd], +8 pad
    __shared__ __align__(16) u16 Vs[64 * 72];        // [hd][kv], +8 pad (V^T)
    __shared__ __align__(16) u16 Ps[4][16 * 72];     // per-wave P [q][kv], +8 pad

    const long base = (long)b * S * 3072;

    // Q fragments: straight vector loads (A-operand layout, same as GEMM frags)
    bf16x8 qf[2];
    {
        const int qrow = q0 + w * 16 + (lane & 15);
#pragma unroll
        for (int c = 0; c < 2; ++c)
            qf[c] = *(const bf16x8*)&qkv[base + (long)qrow * 3072 + h * 64 + c * 32 + (lane >> 4) * 8];
    }

    f32x4 Of[4] = {};
    float mrow[4], lrow[4];
#pragma unroll
    for (int r = 0; r < 4; ++r) { mrow[r] = -1e30f; lrow[r] = 0.0f; }

    for (int kt = 0; kt <= qt; ++kt) {
        __syncthreads();
        // stage K [kv][hd] and V^T [hd][kv]; integer vectors only
#pragma unroll
        for (int it = 0; it < 2; ++it) {
            const int r = it * 32 + (tid >> 3);
            const int cg = (tid & 7) * 8;
            const long grow = base + (long)(kt * 64 + r) * 3072 + h * 64;
            const ushort8 k8 = *(const ushort8*)&qkv[grow + 1024 + cg];
            *(ushort8*)&Ks[r * 72 + cg] = k8;
            const ushort8 v8 = *(const ushort8*)&qkv[grow + 2048 + cg];
#pragma unroll
            for (int j = 0; j < 8; ++j)
                Vs[(cg + j) * 72 + r] = v8[j];
        }
        __syncthreads();

        // S = Q @ K^T   [16 q rows][64 kv], then *0.125 in fp32
        f32x4 Sf[4] = {};
#pragma unroll
        for (int f = 0; f < 4; ++f) {
#pragma unroll
            for (int c = 0; c < 2; ++c) {
                const bf16x8 kf = *(const bf16x8*)&Ks[(f * 16 + (lane & 15)) * 72 + c * 32 + (lane >> 4) * 8];
                Sf[f] = __builtin_amdgcn_mfma_f32_16x16x32_bf16(qf[c], kf, Sf[f], 0, 0, 0);
            }
        }
#pragma unroll
        for (int f = 0; f < 4; ++f)
#pragma unroll
            for (int r = 0; r < 4; ++r)
                Sf[f][r] *= 0.125f;
        // causal mask (only diagonal tile is partial)
        if (kt == qt) {
#pragma unroll
            for (int f = 0; f < 4; ++f) {
                const int kvc = f * 16 + (lane & 15);
#pragma unroll
                for (int r = 0; r < 4; ++r) {
                    const int qr = w * 16 + (lane >> 4) * 4 + r;
                    if (kvc > qr) Sf[f][r] = -1e30f;
                }
            }
        }
        // online softmax (rows live across 16-lane groups)
        float mnew[4], sc[4];
#pragma unroll
        for (int r = 0; r < 4; ++r) {
            float mx = fmaxf(fmaxf(Sf[0][r], Sf[1][r]), fmaxf(Sf[2][r], Sf[3][r]));
#pragma unroll
            for (int d = 1; d < 16; d <<= 1) mx = fmaxf(mx, __shfl_xor(mx, d));
            mnew[r] = fmaxf(mrow[r], mx);
            sc[r] = __expf(mrow[r] - mnew[r]);
            mrow[r] = mnew[r];
        }
#pragma unroll
        for (int f = 0; f < 4; ++f)
#pragma unroll
            for (int r = 0; r < 4; ++r)
                Sf[f][r] = __expf(Sf[f][r] - mnew[r]);
#pragma unroll
        for (int r = 0; r < 4; ++r) {
            float s = Sf[0][r] + Sf[1][r] + Sf[2][r] + Sf[3][r];
#pragma unroll
            for (int d = 1; d < 16; d <<= 1) s += __shfl_xor(s, d);
            lrow[r] = lrow[r] * sc[r] + s;
        }
#pragma unroll
        for (int f = 0; f < 4; ++f)
#pragma unroll
            for (int r = 0; r < 4; ++r)
                Of[f][r] *= sc[r];
        // P -> LDS (bf16 via manual f2bf), per-wave buffer [q within 16][kv]
#pragma unroll
        for (int f = 0; f < 4; ++f)
#pragma unroll
            for (int r = 0; r < 4; ++r)
                Ps[w][((lane >> 4) * 4 + r) * 72 + f * 16 + (lane & 15)] = f2bf(Sf[f][r]);
        __syncthreads();
        // O += P @ V: A = P[q][kv], B = V^T rows (contiguous kv), n = hd
#pragma unroll
        for (int f = 0; f < 4; ++f) {
            const int hd = f * 16 + (lane & 15);
#pragma unroll
            for (int c = 0; c < 2; ++c) {
                const int k0 = c * 32 + (lane >> 4) * 8;
                const bf16x8 pa = *(const bf16x8*)&Ps[w][(lane & 15) * 72 + k0];
                const bf16x8 vb = *(const bf16x8*)&Vs[hd * 72 + k0];
                Of[f] = __builtin_amdgcn_mfma_f32_16x16x32_bf16(pa, vb, Of[f], 0, 0, 0);
            }
        }
    }

    float inv[4];
#pragma unroll
    for (int r = 0; r < 4; ++r) inv[r] = 1.0f / lrow[r];
#pragma unroll
    for (int f = 0; f < 4; ++f) {
        const int col = h * 64 + f * 16 + (lane & 15);
#pragma unroll
        for (int r = 0; r < 4; ++r) {
            const int qrow = q0 + w * 16 + (lane >> 4) * 4 + r;
            outb[((long)b * S + qrow) * 1024 + col] = f2bf(Of[f][r] * inv[r]);
        }
    }
}

// -----------------------------------------------------------------------------
// Workspace plan (56 MiB total; x1 lives in d_out):
//   [0        , 6291456 )  wTa   bf16 [3072][1024]   (dead after qkv GEMM)
//   [6291456  , 8388608 )  wTap  bf16 [1024][1024]   (dead after attn-proj)
//   [8388608  , 16777216)  wTfc  bf16 [4096][1024]
//   [16777216 , 25165824)  wTfp  bf16 [1024][4096]
//   [25165824 , 33554432)  hao   bf16 [4096][1024]   h (ln1 out), then ao (attn out)
//   [33554432 , 58720256)  qkv   bf16 [4096][3072]
//   mb = [25165824, 58720256) bf16 [4096][4096]      (over hao∪qkv, both dead)
//   h2 = [0, 8388608)       bf16 [4096][1024]        (over wTa∪wTap, both dead)
extern "C" void kernel_launch(void* const* d_in, const int* in_sizes, int n_in,
                              void* d_out, int out_size, void* d_ws, size_t ws_size,
                              hipStream_t stream) {
    const float* x      = (const float*)d_in[0];
    const float* ln1_g  = (const float*)d_in[1];
    const float* ln1_b  = (const float*)d_in[2];
    const float* w_attn = (const float*)d_in[3];
    const float* b_attn = (const float*)d_in[4];
    const float* w_ap   = (const float*)d_in[5];
    const float* b_ap   = (const float*)d_in[6];
    const float* ln2_g  = (const float*)d_in[7];
    const float* ln2_b  = (const float*)d_in[8];
    const float* w_fc   = (const float*)d_in[9];
    const float* b_fc   = (const float*)d_in[10];
    const float* w_fp   = (const float*)d_in[11];
    const float* b_fp   = (const float*)d_in[12];
    float* out = (float*)d_out;

    const int R = 4096; // B*S
    char* p = (char*)d_ws;
    u16*   wTa  = (u16*)(p);
    u16*   wTap = (u16*)(p + 6291456);
    u16*   wTfc = (u16*)(p + 8388608);
    u16*   wTfp = (u16*)(p + 16777216);
    u16*   hao  = (u16*)(p + 25165824);   // h, later reused as ao
    u16*   qkv  = (u16*)(p + 33554432);
    u16*   mb   = hao;                    // spans hao + qkv (33,554,432 B)
    u16*   h2   = wTa;                    // spans wTa + wTap (8,388,608 B)
    float* x1   = out;                    // residual stream lives in d_out

    const dim3 tb(32, 8);
    tcvt_kernel<<<dim3(3072 / 32, 1024 / 32), tb, 0, stream>>>(w_attn, wTa, 1024, 3072);
    tcvt_kernel<<<dim3(1024 / 32, 1024 / 32), tb, 0, stream>>>(w_ap, wTap, 1024, 1024);
    tcvt_kernel<<<dim3(4096 / 32, 1024 / 32), tb, 0, stream>>>(w_fc, wTfc, 1024, 4096);
    tcvt_kernel<<<dim3(1024 / 32, 4096 / 32), tb, 0, stream>>>(w_fp, wTfp, 4096, 1024);

    ln_kernel<<<R, 256, 0, stream>>>(x, ln1_g, ln1_b, hao);
    gemm_bt<0><<<dim3(32, 24), 256, 0, stream>>>(hao, wTa, b_attn, nullptr, qkv, R, 3072, 1024);
    attn_kernel<<<dim3(32, 32), 256, 0, stream>>>(qkv, hao);
    gemm_bt<2><<<dim3(32, 8), 256, 0, stream>>>(hao, wTap, b_ap, x, x1, R, 1024, 1024);
    ln_kernel<<<R, 256, 0, stream>>>(x1, ln2_g, ln2_b, h2);
    gemm_bt<1><<<dim3(32, 32), 256, 0, stream>>>(h2, wTfc, b_fc, nullptr, mb, R, 4096, 1024);
    gemm_bt<2><<<dim3(32, 8), 256, 0, stream>>>(mb, wTfp, b_fp, x1, out, R, 1024, 4096);
}

// Round 5
// 340.279 us; speedup vs baseline: 14.7176x; 1.2271x over previous
//
#include <hip/hip_runtime.h>
#include <hip/hip_bf16.h>
#include <math.h>

typedef __bf16 bf16_t;
typedef bf16_t bf16x8 __attribute__((ext_vector_type(8)));
typedef float f32x4 __attribute__((ext_vector_type(4)));
typedef unsigned short u16;
typedef u16 ushort8 __attribute__((ext_vector_type(8)));

static __device__ __forceinline__ u16 f2bf(float f) {
    unsigned u = __builtin_bit_cast(unsigned, f);
    u += 0x7FFFu + ((u >> 16) & 1u);
    return (u16)(u >> 16);
}

// ---------------- LayerNorm: fp32 in -> bf16 out, one block per row (D=1024) --
__global__ __launch_bounds__(256) void ln_kernel(
    const float* __restrict__ x, const float* __restrict__ g,
    const float* __restrict__ be, u16* __restrict__ out)
{
    const int row = blockIdx.x;
    const int tid = threadIdx.x;
    const float4 v = ((const float4*)(x + (long)row * 1024))[tid];
    float s = v.x + v.y + v.z + v.w;
#pragma unroll
    for (int d = 32; d >= 1; d >>= 1) s += __shfl_xor(s, d);
    __shared__ float r1[4], r2[4];
    if ((tid & 63) == 0) r1[tid >> 6] = s;
    __syncthreads();
    const float mean = (r1[0] + r1[1] + r1[2] + r1[3]) * (1.0f / 1024.0f);
    const float dx = v.x - mean, dy = v.y - mean, dz = v.z - mean, dw = v.w - mean;
    float sq = dx * dx + dy * dy + dz * dz + dw * dw;
#pragma unroll
    for (int d = 32; d >= 1; d >>= 1) sq += __shfl_xor(sq, d);
    if ((tid & 63) == 0) r2[tid >> 6] = sq;
    __syncthreads();
    const float var = (r2[0] + r2[1] + r2[2] + r2[3]) * (1.0f / 1024.0f);
    const float rstd = rsqrtf(var + 1e-5f);
    const float4 gg = ((const float4*)g)[tid];
    const float4 bb = ((const float4*)be)[tid];
    ushort4 o;
    o.x = f2bf(dx * rstd * gg.x + bb.x);
    o.y = f2bf(dy * rstd * gg.y + bb.y);
    o.z = f2bf(dz * rstd * gg.z + bb.z);
    o.w = f2bf(dw * rstd * gg.w + bb.w);
    *(ushort4*)&out[(long)row * 1024 + tid * 4] = o;
}

// ---------------- Transpose + cvt: fp32 [R][C] -> bf16 [C][R] ----------------
__global__ __launch_bounds__(256) void tcvt_kernel(
    const float* __restrict__ in, u16* __restrict__ outT, int R, int C)
{
    __shared__ float tile[32][33];
    const int tx = threadIdx.x, ty = threadIdx.y; // 32 x 8
    const int c0 = blockIdx.x * 32, r0 = blockIdx.y * 32;
#pragma unroll
    for (int i = 0; i < 4; ++i)
        tile[ty + i * 8][tx] = in[(long)(r0 + ty + i * 8) * C + c0 + tx];
    __syncthreads();
#pragma unroll
    for (int i = 0; i < 4; ++i)
        outT[(long)(c0 + ty + i * 8) * R + r0 + tx] = f2bf(tile[tx][ty + i * 8]);
}

// ---------------- GEMM: C[M,N] = A[M,K] @ Bt[N,K]^T + bias, m97 structure ----
// EPI 0: store bf16. EPI 1: exact GELU -> bf16. EPI 2: += fp32 residual -> fp32.
template <int EPI>
__global__ __launch_bounds__(256) void gemm_bt(
    const u16* __restrict__ A, const u16* __restrict__ Bt,
    const float* __restrict__ bias, const float* __restrict__ resid,
    void* __restrict__ C, int M, int N, int K)
{
    __shared__ __align__(16) u16 As[128 * 32];
    __shared__ __align__(16) u16 Bs[128 * 32];
    const int tid = threadIdx.x;
    const int lane = tid & 63;
    const int w = tid >> 6;
    const int wm = w >> 1, wn = w & 1;
    const int bm = blockIdx.x, bn = blockIdx.y;
    f32x4 acc[4][4] = {};

    const u16* Ablk = A + (long)bm * 128 * K;
    const u16* Bblk = Bt + (long)bn * 128 * K;

    for (int kb = 0; kb < K; kb += 32) {
        __syncthreads();
#pragma unroll
        for (int i = 0; i < 2; ++i) {
            const int o = (w * 2 + i) * 512 + lane * 8;
            const int row = o >> 5, kk = o & 31;
            const u16* ga = Ablk + (long)row * K + kb + kk;
            const u16* gb = Bblk + (long)row * K + kb + kk;
            __builtin_amdgcn_global_load_lds(
                (const __attribute__((address_space(1))) void*)ga,
                (__attribute__((address_space(3))) void*)(As + (w * 2 + i) * 512),
                16, 0, 0);
            __builtin_amdgcn_global_load_lds(
                (const __attribute__((address_space(1))) void*)gb,
                (__attribute__((address_space(3))) void*)(Bs + (w * 2 + i) * 512),
                16, 0, 0);
        }
        __syncthreads();
        bf16x8 af[4], bfr[4];
#pragma unroll
        for (int m = 0; m < 4; ++m)
            af[m] = *(const bf16x8*)&As[(wm * 64 + m * 16 + (lane & 15)) * 32 + (lane >> 4) * 8];
#pragma unroll
        for (int n = 0; n < 4; ++n)
            bfr[n] = *(const bf16x8*)&Bs[(wn * 64 + n * 16 + (lane & 15)) * 32 + (lane >> 4) * 8];
#pragma unroll
        for (int m = 0; m < 4; ++m)
#pragma unroll
            for (int n = 0; n < 4; ++n)
                acc[m][n] = __builtin_amdgcn_mfma_f32_16x16x32_bf16(af[m], bfr[n], acc[m][n], 0, 0, 0);
    }

    const int rowBase = bm * 128 + wm * 64;
    const int colBase = bn * 128 + wn * 64;
#pragma unroll
    for (int n = 0; n < 4; ++n) {
        const int col = colBase + n * 16 + (lane & 15);
        const float bv = bias[col];
#pragma unroll
        for (int m = 0; m < 4; ++m) {
#pragma unroll
            for (int r = 0; r < 4; ++r) {
                const int row = rowBase + m * 16 + (lane >> 4) * 4 + r;
                float v = acc[m][n][r] + bv;
                if constexpr (EPI == 1) v = 0.5f * v * (1.0f + erff(v * 0.70710678118654752f));
                if constexpr (EPI == 2) {
                    ((float*)C)[(long)row * N + col] = v + resid[(long)row * N + col];
                } else {
                    ((u16*)C)[(long)row * N + col] = f2bf(v);
                }
            }
        }
    }
}

// ---------------- Flash attention v3 (causal), paired q-tiles, dbuf K/V ------
// qkv: bf16 [B*S][3072] (q|k|v). out: bf16 [B*S][1024], col = h*64 + d.
// Block ipair handles q-tiles {ipair, 31-ipair}: (i+1)+(32-i)=33 iters/block.
// K/V double-buffered in LDS; next tile's global loads issued into regs before
// compute; ONE barrier per iteration. Compute math identical to passing v2.
__global__ __launch_bounds__(256) void attn_kernel(
    const u16* __restrict__ qkv, u16* __restrict__ outb)
{
    const int S = 2048;
    const int ipair = blockIdx.x;        // 0..15
    const int bh = blockIdx.y;           // b*16 + h
    const int b = bh >> 4, h = bh & 15;
    const int tid = threadIdx.x, lane = tid & 63, w = tid >> 6;
    __shared__ __align__(16) u16 Ks[2][64 * 72];     // [kv][hd], +8 pad
    __shared__ __align__(16) u16 Vs[2][64 * 72];     // [hd][kv], +8 pad (V^T)
    __shared__ __align__(16) u16 Ps[4][16 * 72];     // per-wave P [q][kv], +8 pad

    const long base = (long)b * S * 3072;
    const int rstage = tid >> 3;         // 0..31 (staging row within half-tile)
    const int cg = (tid & 7) * 8;        // staging col group
    const u16* kbase = qkv + base + 1024 + h * 64 + cg;
    const u16* vbase = qkv + base + 2048 + h * 64 + cg;

    for (int half = 0; half < 2; ++half) {
        const int qt = half ? 31 - ipair : ipair;
        const int q0 = qt * 64;

        // Q fragments: straight vector loads (A-operand layout)
        bf16x8 qf[2];
        {
            const int qrow = q0 + w * 16 + (lane & 15);
#pragma unroll
            for (int c = 0; c < 2; ++c)
                qf[c] = *(const bf16x8*)&qkv[base + (long)qrow * 3072 + h * 64 + c * 32 + (lane >> 4) * 8];
        }

        f32x4 Of[4] = {};
        float mrow[4], lrow[4];
#pragma unroll
        for (int r = 0; r < 4; ++r) { mrow[r] = -1e30f; lrow[r] = 0.0f; }

        // prologue: fetch kt=0 into regs, then stage into buf 0
        ushort8 kr[2], vr[2];
#pragma unroll
        for (int it = 0; it < 2; ++it) {
            const long ro = (long)(it * 32 + rstage) * 3072;
            kr[it] = *(const ushort8*)&kbase[ro];
            vr[it] = *(const ushort8*)&vbase[ro];
        }
        __syncthreads();   // protect buffers from previous half's readers
#pragma unroll
        for (int it = 0; it < 2; ++it) {
            const int r = it * 32 + rstage;
            *(ushort8*)&Ks[0][r * 72 + cg] = kr[it];
#pragma unroll
            for (int j = 0; j < 8; ++j)
                Vs[0][(cg + j) * 72 + r] = vr[it][j];
        }

        for (int kt = 0; kt <= qt; ++kt) {
            const int cur = kt & 1;
            // prefetch next tile into regs (latency hidden under compute)
            if (kt < qt) {
#pragma unroll
                for (int it = 0; it < 2; ++it) {
                    const long ro = (long)((kt + 1) * 64 + it * 32 + rstage) * 3072;
                    kr[it] = *(const ushort8*)&kbase[ro];
                    vr[it] = *(const ushort8*)&vbase[ro];
                }
            }
            __syncthreads();   // buf[cur] staged & visible to all waves

            // S = Q @ K^T   [16 q rows][64 kv], then *0.125 in fp32
            f32x4 Sf[4] = {};
#pragma unroll
            for (int f = 0; f < 4; ++f) {
#pragma unroll
                for (int c = 0; c < 2; ++c) {
                    const bf16x8 kf = *(const bf16x8*)&Ks[cur][(f * 16 + (lane & 15)) * 72 + c * 32 + (lane >> 4) * 8];
                    Sf[f] = __builtin_amdgcn_mfma_f32_16x16x32_bf16(qf[c], kf, Sf[f], 0, 0, 0);
                }
            }
#pragma unroll
            for (int f = 0; f < 4; ++f)
#pragma unroll
                for (int r = 0; r < 4; ++r)
                    Sf[f][r] *= 0.125f;
            // causal mask (only diagonal tile is partial)
            if (kt == qt) {
#pragma unroll
                for (int f = 0; f < 4; ++f) {
                    const int kvc = f * 16 + (lane & 15);
#pragma unroll
                    for (int r = 0; r < 4; ++r) {
                        const int qr = w * 16 + (lane >> 4) * 4 + r;
                        if (kvc > qr) Sf[f][r] = -1e30f;
                    }
                }
            }
            // online softmax (rows live across 16-lane groups)
            float mnew[4], sc[4];
#pragma unroll
            for (int r = 0; r < 4; ++r) {
                float mx = fmaxf(fmaxf(Sf[0][r], Sf[1][r]), fmaxf(Sf[2][r], Sf[3][r]));
#pragma unroll
                for (int d = 1; d < 16; d <<= 1) mx = fmaxf(mx, __shfl_xor(mx, d));
                mnew[r] = fmaxf(mrow[r], mx);
                sc[r] = __expf(mrow[r] - mnew[r]);
                mrow[r] = mnew[r];
            }
#pragma unroll
            for (int f = 0; f < 4; ++f)
#pragma unroll
                for (int r = 0; r < 4; ++r)
                    Sf[f][r] = __expf(Sf[f][r] - mnew[r]);
#pragma unroll
            for (int r = 0; r < 4; ++r) {
                float s = Sf[0][r] + Sf[1][r] + Sf[2][r] + Sf[3][r];
#pragma unroll
                for (int d = 1; d < 16; d <<= 1) s += __shfl_xor(s, d);
                lrow[r] = lrow[r] * sc[r] + s;
            }
#pragma unroll
            for (int f = 0; f < 4; ++f)
#pragma unroll
                for (int r = 0; r < 4; ++r)
                    Of[f][r] *= sc[r];
            // P -> LDS (per-wave buffer; no barrier needed, same-wave use)
#pragma unroll
            for (int f = 0; f < 4; ++f)
#pragma unroll
                for (int r = 0; r < 4; ++r)
                    Ps[w][((lane >> 4) * 4 + r) * 72 + f * 16 + (lane & 15)] = f2bf(Sf[f][r]);
            // O += P @ V
#pragma unroll
            for (int f = 0; f < 4; ++f) {
                const int hd = f * 16 + (lane & 15);
#pragma unroll
                for (int c = 0; c < 2; ++c) {
                    const int k0 = c * 32 + (lane >> 4) * 8;
                    const bf16x8 pa = *(const bf16x8*)&Ps[w][(lane & 15) * 72 + k0];
                    const bf16x8 vb = *(const bf16x8*)&Vs[cur][hd * 72 + k0];
                    Of[f] = __builtin_amdgcn_mfma_f32_16x16x32_bf16(pa, vb, Of[f], 0, 0, 0);
                }
            }
            // stage prefetched tile into buf[cur^1] (visible after next barrier)
            if (kt < qt) {
#pragma unroll
                for (int it = 0; it < 2; ++it) {
                    const int r = it * 32 + rstage;
                    *(ushort8*)&Ks[cur ^ 1][r * 72 + cg] = kr[it];
#pragma unroll
                    for (int j = 0; j < 8; ++j)
                        Vs[cur ^ 1][(cg + j) * 72 + r] = vr[it][j];
                }
            }
        }

        float inv[4];
#pragma unroll
        for (int r = 0; r < 4; ++r) inv[r] = 1.0f / lrow[r];
#pragma unroll
        for (int f = 0; f < 4; ++f) {
            const int col = h * 64 + f * 16 + (lane & 15);
#pragma unroll
            for (int r = 0; r < 4; ++r) {
                const int qrow = q0 + w * 16 + (lane >> 4) * 4 + r;
                outb[((long)b * S + qrow) * 1024 + col] = f2bf(Of[f][r] * inv[r]);
            }
        }
    }
}

// -----------------------------------------------------------------------------
// Workspace plan (56 MiB total; x1 lives in d_out):
//   [0        , 6291456 )  wTa   bf16 [3072][1024]   (dead after qkv GEMM)
//   [6291456  , 8388608 )  wTap  bf16 [1024][1024]   (dead after attn-proj)
//   [8388608  , 16777216)  wTfc  bf16 [4096][1024]
//   [16777216 , 25165824)  wTfp  bf16 [1024][4096]
//   [25165824 , 33554432)  hao   bf16 [4096][1024]   h (ln1 out), then ao (attn out)
//   [33554432 , 58720256)  qkv   bf16 [4096][3072]
//   mb = [25165824, 58720256) bf16 [4096][4096]      (over hao∪qkv, both dead)
//   h2 = [0, 8388608)       bf16 [4096][1024]        (over wTa∪wTap, both dead)
extern "C" void kernel_launch(void* const* d_in, const int* in_sizes, int n_in,
                              void* d_out, int out_size, void* d_ws, size_t ws_size,
                              hipStream_t stream) {
    const float* x      = (const float*)d_in[0];
    const float* ln1_g  = (const float*)d_in[1];
    const float* ln1_b  = (const float*)d_in[2];
    const float* w_attn = (const float*)d_in[3];
    const float* b_attn = (const float*)d_in[4];
    const float* w_ap   = (const float*)d_in[5];
    const float* b_ap   = (const float*)d_in[6];
    const float* ln2_g  = (const float*)d_in[7];
    const float* ln2_b  = (const float*)d_in[8];
    const float* w_fc   = (const float*)d_in[9];
    const float* b_fc   = (const float*)d_in[10];
    const float* w_fp   = (const float*)d_in[11];
    const float* b_fp   = (const float*)d_in[12];
    float* out = (float*)d_out;

    const int R = 4096; // B*S
    char* p = (char*)d_ws;
    u16*   wTa  = (u16*)(p);
    u16*   wTap = (u16*)(p + 6291456);
    u16*   wTfc = (u16*)(p + 8388608);
    u16*   wTfp = (u16*)(p + 16777216);
    u16*   hao  = (u16*)(p + 25165824);   // h, later reused as ao
    u16*   qkv  = (u16*)(p + 33554432);
    u16*   mb   = hao;                    // spans hao + qkv (33,554,432 B)
    u16*   h2   = wTa;                    // spans wTa + wTap (8,388,608 B)
    float* x1   = out;                    // residual stream lives in d_out

    const dim3 tb(32, 8);
    tcvt_kernel<<<dim3(3072 / 32, 1024 / 32), tb, 0, stream>>>(w_attn, wTa, 1024, 3072);
    tcvt_kernel<<<dim3(1024 / 32, 1024 / 32), tb, 0, stream>>>(w_ap, wTap, 1024, 1024);
    tcvt_kernel<<<dim3(4096 / 32, 1024 / 32), tb, 0, stream>>>(w_fc, wTfc, 1024, 4096);
    tcvt_kernel<<<dim3(1024 / 32, 4096 / 32), tb, 0, stream>>>(w_fp, wTfp, 4096, 1024);

    ln_kernel<<<R, 256, 0, stream>>>(x, ln1_g, ln1_b, hao);
    gemm_bt<0><<<dim3(32, 24), 256, 0, stream>>>(hao, wTa, b_attn, nullptr, qkv, R, 3072, 1024);
    attn_kernel<<<dim3(16, 32), 256, 0, stream>>>(qkv, hao);
    gemm_bt<2><<<dim3(32, 8), 256, 0, stream>>>(hao, wTap, b_ap, x, x1, R, 1024, 1024);
    ln_kernel<<<R, 256, 0, stream>>>(x1, ln2_g, ln2_b, h2);
    gemm_bt<1><<<dim3(32, 32), 256, 0, stream>>>(h2, wTfc, b_fc, nullptr, mb, R, 4096, 1024);
    gemm_bt<2><<<dim3(32, 8), 256, 0, stream>>>(mb, wTfp, b_fp, x1, out, R, 1024, 4096);
}

// Round 6
// 312.893 us; speedup vs baseline: 16.0057x; 1.0875x over previous
//
#include <hip/hip_runtime.h>
#include <hip/hip_bf16.h>
#include <math.h>

typedef __bf16 bf16_t;
typedef bf16_t bf16x8 __attribute__((ext_vector_type(8)));
typedef float f32x4 __attribute__((ext_vector_type(4)));
typedef unsigned short u16;
typedef u16 ushort8 __attribute__((ext_vector_type(8)));

static __device__ __forceinline__ u16 f2bf(float f) {
    unsigned u = __builtin_bit_cast(unsigned, f);
    u += 0x7FFFu + ((u >> 16) & 1u);
    return (u16)(u >> 16);
}

// ---------------- LayerNorm: fp32 in -> bf16 out, one block per row (D=1024) --
__global__ __launch_bounds__(256) void ln_kernel(
    const float* __restrict__ x, const float* __restrict__ g,
    const float* __restrict__ be, u16* __restrict__ out)
{
    const int row = blockIdx.x;
    const int tid = threadIdx.x;
    const float4 v = ((const float4*)(x + (long)row * 1024))[tid];
    float s = v.x + v.y + v.z + v.w;
#pragma unroll
    for (int d = 32; d >= 1; d >>= 1) s += __shfl_xor(s, d);
    __shared__ float r1[4], r2[4];
    if ((tid & 63) == 0) r1[tid >> 6] = s;
    __syncthreads();
    const float mean = (r1[0] + r1[1] + r1[2] + r1[3]) * (1.0f / 1024.0f);
    const float dx = v.x - mean, dy = v.y - mean, dz = v.z - mean, dw = v.w - mean;
    float sq = dx * dx + dy * dy + dz * dz + dw * dw;
#pragma unroll
    for (int d = 32; d >= 1; d >>= 1) sq += __shfl_xor(sq, d);
    if ((tid & 63) == 0) r2[tid >> 6] = sq;
    __syncthreads();
    const float var = (r2[0] + r2[1] + r2[2] + r2[3]) * (1.0f / 1024.0f);
    const float rstd = rsqrtf(var + 1e-5f);
    const float4 gg = ((const float4*)g)[tid];
    const float4 bb = ((const float4*)be)[tid];
    ushort4 o;
    o.x = f2bf(dx * rstd * gg.x + bb.x);
    o.y = f2bf(dy * rstd * gg.y + bb.y);
    o.z = f2bf(dz * rstd * gg.z + bb.z);
    o.w = f2bf(dw * rstd * gg.w + bb.w);
    *(ushort4*)&out[(long)row * 1024 + tid * 4] = o;
}

// ---------------- Transpose + cvt: fp32 [R][C] -> bf16 [C][R] ----------------
__global__ __launch_bounds__(256) void tcvt_kernel(
    const float* __restrict__ in, u16* __restrict__ outT, int R, int C)
{
    __shared__ float tile[32][33];
    const int tx = threadIdx.x, ty = threadIdx.y; // 32 x 8
    const int c0 = blockIdx.x * 32, r0 = blockIdx.y * 32;
#pragma unroll
    for (int i = 0; i < 4; ++i)
        tile[ty + i * 8][tx] = in[(long)(r0 + ty + i * 8) * C + c0 + tx];
    __syncthreads();
#pragma unroll
    for (int i = 0; i < 4; ++i)
        outT[(long)(c0 + ty + i * 8) * R + r0 + tx] = f2bf(tile[tx][ty + i * 8]);
}

// ---------------- GEMM: C[M,N] = A[M,K] @ Bt[N,K]^T + bias, m97 structure ----
// Tile BM x 128. BM=128: 2x2 waves (4x4 frags). BM=64: 1x4 waves (4x2 frags),
// grid doubles -> 2 blocks/CU for skinny-N GEMMs.
// EPI 0: store bf16. EPI 1: exact GELU -> bf16. EPI 2: += fp32 residual -> fp32.
template <int BM, int EPI>
__global__ __launch_bounds__(256) void gemm_bt(
    const u16* __restrict__ A, const u16* __restrict__ Bt,
    const float* __restrict__ bias, const float* __restrict__ resid,
    void* __restrict__ C, int M, int N, int K)
{
    constexpr int WN = (BM == 128) ? 2 : 4;   // waves along N
    constexpr int MR = BM / (4 / WN) / 16;    // m-frags per wave (4)
    constexpr int NR = 128 / WN / 16;         // n-frags per wave (4 or 2)
    __shared__ __align__(16) u16 As[BM * 32];
    __shared__ __align__(16) u16 Bs[128 * 32];
    const int tid = threadIdx.x;
    const int lane = tid & 63;
    const int w = tid >> 6;
    const int wm = w / WN, wn = w % WN;
    const int bm = blockIdx.x, bn = blockIdx.y;
    f32x4 acc[MR][NR] = {};

    const u16* Ablk = A + (long)bm * BM * K;
    const u16* Bblk = Bt + (long)bn * 128 * K;

    for (int kb = 0; kb < K; kb += 32) {
        __syncthreads();
#pragma unroll
        for (int i = 0; i < BM / 64; ++i) {
            const int o = (w * (BM / 64) + i) * 512 + lane * 8;
            const int row = o >> 5, kk = o & 31;
            __builtin_amdgcn_global_load_lds(
                (const __attribute__((address_space(1))) void*)(Ablk + (long)row * K + kb + kk),
                (__attribute__((address_space(3))) void*)(As + (w * (BM / 64) + i) * 512),
                16, 0, 0);
        }
#pragma unroll
        for (int i = 0; i < 2; ++i) {
            const int o = (w * 2 + i) * 512 + lane * 8;
            const int row = o >> 5, kk = o & 31;
            __builtin_amdgcn_global_load_lds(
                (const __attribute__((address_space(1))) void*)(Bblk + (long)row * K + kb + kk),
                (__attribute__((address_space(3))) void*)(Bs + (w * 2 + i) * 512),
                16, 0, 0);
        }
        __syncthreads();
        bf16x8 af[MR], bfr[NR];
#pragma unroll
        for (int m = 0; m < MR; ++m)
            af[m] = *(const bf16x8*)&As[(wm * MR * 16 + m * 16 + (lane & 15)) * 32 + (lane >> 4) * 8];
#pragma unroll
        for (int n = 0; n < NR; ++n)
            bfr[n] = *(const bf16x8*)&Bs[(wn * NR * 16 + n * 16 + (lane & 15)) * 32 + (lane >> 4) * 8];
#pragma unroll
        for (int m = 0; m < MR; ++m)
#pragma unroll
            for (int n = 0; n < NR; ++n)
                acc[m][n] = __builtin_amdgcn_mfma_f32_16x16x32_bf16(af[m], bfr[n], acc[m][n], 0, 0, 0);
    }

    const int rowBase = bm * BM + wm * MR * 16;
    const int colBase = bn * 128 + wn * NR * 16;
#pragma unroll
    for (int n = 0; n < NR; ++n) {
        const int col = colBase + n * 16 + (lane & 15);
        const float bv = bias[col];
#pragma unroll
        for (int m = 0; m < MR; ++m) {
#pragma unroll
            for (int r = 0; r < 4; ++r) {
                const int row = rowBase + m * 16 + (lane >> 4) * 4 + r;
                float v = acc[m][n][r] + bv;
                if constexpr (EPI == 1) v = 0.5f * v * (1.0f + erff(v * 0.70710678118654752f));
                if constexpr (EPI == 2) {
                    ((float*)C)[(long)row * N + col] = v + resid[(long)row * N + col];
                } else {
                    ((u16*)C)[(long)row * N + col] = f2bf(v);
                }
            }
        }
    }
}

// ---------------- Flash attention v4 (causal), paired q-tiles, dbuf K/V ------
// v3 + XOR-swizzled V^T LDS layout (kills the 16-way write bank conflict):
//   Vs[hd][kv] stored at kv' = kv ^ (hd & 56); reads use k0 ^ (hd & 56),
//   which preserves 16B-aligned b128 reads since k0 and the swizzle are
//   both multiples of 8.
__global__ __launch_bounds__(256) void attn_kernel(
    const u16* __restrict__ qkv, u16* __restrict__ outb)
{
    const int S = 2048;
    const int ipair = blockIdx.x;        // 0..15
    const int bh = blockIdx.y;           // b*16 + h
    const int b = bh >> 4, h = bh & 15;
    const int tid = threadIdx.x, lane = tid & 63, w = tid >> 6;
    __shared__ __align__(16) u16 Ks[2][64 * 72];     // [kv][hd], +8 pad
    __shared__ __align__(16) u16 Vs[2][64 * 72];     // [hd][kv^swz], +8 pad
    __shared__ __align__(16) u16 Ps[4][16 * 72];     // per-wave P [q][kv], +8 pad

    const long base = (long)b * S * 3072;
    const int rstage = tid >> 3;         // 0..31 (staging row within half-tile)
    const int cg = (tid & 7) * 8;        // staging col group
    const int sw = cg;                   // (cg>>3)<<3 == cg: V swizzle bits
    const u16* kbase = qkv + base + 1024 + h * 64 + cg;
    const u16* vbase = qkv + base + 2048 + h * 64 + cg;

    for (int half = 0; half < 2; ++half) {
        const int qt = half ? 31 - ipair : ipair;
        const int q0 = qt * 64;

        // Q fragments: straight vector loads (A-operand layout)
        bf16x8 qf[2];
        {
            const int qrow = q0 + w * 16 + (lane & 15);
#pragma unroll
            for (int c = 0; c < 2; ++c)
                qf[c] = *(const bf16x8*)&qkv[base + (long)qrow * 3072 + h * 64 + c * 32 + (lane >> 4) * 8];
        }

        f32x4 Of[4] = {};
        float mrow[4], lrow[4];
#pragma unroll
        for (int r = 0; r < 4; ++r) { mrow[r] = -1e30f; lrow[r] = 0.0f; }

        // prologue: fetch kt=0 into regs, then stage into buf 0
        ushort8 kr[2], vr[2];
#pragma unroll
        for (int it = 0; it < 2; ++it) {
            const long ro = (long)(it * 32 + rstage) * 3072;
            kr[it] = *(const ushort8*)&kbase[ro];
            vr[it] = *(const ushort8*)&vbase[ro];
        }
        __syncthreads();   // protect buffers from previous half's readers
#pragma unroll
        for (int it = 0; it < 2; ++it) {
            const int r = it * 32 + rstage;
            *(ushort8*)&Ks[0][r * 72 + cg] = kr[it];
#pragma unroll
            for (int j = 0; j < 8; ++j)
                Vs[0][(cg + j) * 72 + (r ^ sw)] = vr[it][j];
        }

        for (int kt = 0; kt <= qt; ++kt) {
            const int cur = kt & 1;
            // prefetch next tile into regs (latency hidden under compute)
            if (kt < qt) {
#pragma unroll
                for (int it = 0; it < 2; ++it) {
                    const long ro = (long)((kt + 1) * 64 + it * 32 + rstage) * 3072;
                    kr[it] = *(const ushort8*)&kbase[ro];
                    vr[it] = *(const ushort8*)&vbase[ro];
                }
            }
            __syncthreads();   // buf[cur] staged & visible to all waves

            // S = Q @ K^T   [16 q rows][64 kv], then *0.125 in fp32
            f32x4 Sf[4] = {};
#pragma unroll
            for (int f = 0; f < 4; ++f) {
#pragma unroll
                for (int c = 0; c < 2; ++c) {
                    const bf16x8 kf = *(const bf16x8*)&Ks[cur][(f * 16 + (lane & 15)) * 72 + c * 32 + (lane >> 4) * 8];
                    Sf[f] = __builtin_amdgcn_mfma_f32_16x16x32_bf16(qf[c], kf, Sf[f], 0, 0, 0);
                }
            }
#pragma unroll
            for (int f = 0; f < 4; ++f)
#pragma unroll
                for (int r = 0; r < 4; ++r)
                    Sf[f][r] *= 0.125f;
            // causal mask (only diagonal tile is partial)
            if (kt == qt) {
#pragma unroll
                for (int f = 0; f < 4; ++f) {
                    const int kvc = f * 16 + (lane & 15);
#pragma unroll
                    for (int r = 0; r < 4; ++r) {
                        const int qr = w * 16 + (lane >> 4) * 4 + r;
                        if (kvc > qr) Sf[f][r] = -1e30f;
                    }
                }
            }
            // online softmax (rows live across 16-lane groups)
            float mnew[4], sc[4];
#pragma unroll
            for (int r = 0; r < 4; ++r) {
                float mx = fmaxf(fmaxf(Sf[0][r], Sf[1][r]), fmaxf(Sf[2][r], Sf[3][r]));
#pragma unroll
                for (int d = 1; d < 16; d <<= 1) mx = fmaxf(mx, __shfl_xor(mx, d));
                mnew[r] = fmaxf(mrow[r], mx);
                sc[r] = __expf(mrow[r] - mnew[r]);
                mrow[r] = mnew[r];
            }
#pragma unroll
            for (int f = 0; f < 4; ++f)
#pragma unroll
                for (int r = 0; r < 4; ++r)
                    Sf[f][r] = __expf(Sf[f][r] - mnew[r]);
#pragma unroll
            for (int r = 0; r < 4; ++r) {
                float s = Sf[0][r] + Sf[1][r] + Sf[2][r] + Sf[3][r];
#pragma unroll
                for (int d = 1; d < 16; d <<= 1) s += __shfl_xor(s, d);
                lrow[r] = lrow[r] * sc[r] + s;
            }
#pragma unroll
            for (int f = 0; f < 4; ++f)
#pragma unroll
                for (int r = 0; r < 4; ++r)
                    Of[f][r] *= sc[r];
            // P -> LDS (per-wave buffer; no barrier needed, same-wave use)
#pragma unroll
            for (int f = 0; f < 4; ++f)
#pragma unroll
                for (int r = 0; r < 4; ++r)
                    Ps[w][((lane >> 4) * 4 + r) * 72 + f * 16 + (lane & 15)] = f2bf(Sf[f][r]);
            // O += P @ V (V reads de-swizzled: (k0+j)^s == (k0^s)+j)
#pragma unroll
            for (int f = 0; f < 4; ++f) {
                const int hd = f * 16 + (lane & 15);
#pragma unroll
                for (int c = 0; c < 2; ++c) {
                    const int k0 = c * 32 + (lane >> 4) * 8;
                    const bf16x8 pa = *(const bf16x8*)&Ps[w][(lane & 15) * 72 + k0];
                    const bf16x8 vb = *(const bf16x8*)&Vs[cur][hd * 72 + (k0 ^ (hd & 56))];
                    Of[f] = __builtin_amdgcn_mfma_f32_16x16x32_bf16(pa, vb, Of[f], 0, 0, 0);
                }
            }
            // stage prefetched tile into buf[cur^1] (visible after next barrier)
            if (kt < qt) {
#pragma unroll
                for (int it = 0; it < 2; ++it) {
                    const int r = it * 32 + rstage;
                    *(ushort8*)&Ks[cur ^ 1][r * 72 + cg] = kr[it];
#pragma unroll
                    for (int j = 0; j < 8; ++j)
                        Vs[cur ^ 1][(cg + j) * 72 + (r ^ sw)] = vr[it][j];
                }
            }
        }

        float inv[4];
#pragma unroll
        for (int r = 0; r < 4; ++r) inv[r] = 1.0f / lrow[r];
#pragma unroll
        for (int f = 0; f < 4; ++f) {
            const int col = h * 64 + f * 16 + (lane & 15);
#pragma unroll
            for (int r = 0; r < 4; ++r) {
                const int qrow = q0 + w * 16 + (lane >> 4) * 4 + r;
                outb[((long)b * S + qrow) * 1024 + col] = f2bf(Of[f][r] * inv[r]);
            }
        }
    }
}

// -----------------------------------------------------------------------------
// Workspace plan (56 MiB total; x1 lives in d_out):
//   [0        , 6291456 )  wTa   bf16 [3072][1024]   (dead after qkv GEMM)
//   [6291456  , 8388608 )  wTap  bf16 [1024][1024]   (dead after attn-proj)
//   [8388608  , 16777216)  wTfc  bf16 [4096][1024]
//   [16777216 , 25165824)  wTfp  bf16 [1024][4096]
//   [25165824 , 33554432)  hao   bf16 [4096][1024]   h (ln1 out), then ao (attn out)
//   [33554432 , 58720256)  qkv   bf16 [4096][3072]
//   mb = [25165824, 58720256) bf16 [4096][4096]      (over hao∪qkv, both dead)
//   h2 = [0, 8388608)       bf16 [4096][1024]        (over wTa∪wTap, both dead)
extern "C" void kernel_launch(void* const* d_in, const int* in_sizes, int n_in,
                              void* d_out, int out_size, void* d_ws, size_t ws_size,
                              hipStream_t stream) {
    const float* x      = (const float*)d_in[0];
    const float* ln1_g  = (const float*)d_in[1];
    const float* ln1_b  = (const float*)d_in[2];
    const float* w_attn = (const float*)d_in[3];
    const float* b_attn = (const float*)d_in[4];
    const float* w_ap   = (const float*)d_in[5];
    const float* b_ap   = (const float*)d_in[6];
    const float* ln2_g  = (const float*)d_in[7];
    const float* ln2_b  = (const float*)d_in[8];
    const float* w_fc   = (const float*)d_in[9];
    const float* b_fc   = (const float*)d_in[10];
    const float* w_fp   = (const float*)d_in[11];
    const float* b_fp   = (const float*)d_in[12];
    float* out = (float*)d_out;

    const int R = 4096; // B*S
    char* p = (char*)d_ws;
    u16*   wTa  = (u16*)(p);
    u16*   wTap = (u16*)(p + 6291456);
    u16*   wTfc = (u16*)(p + 8388608);
    u16*   wTfp = (u16*)(p + 16777216);
    u16*   hao  = (u16*)(p + 25165824);   // h, later reused as ao
    u16*   qkv  = (u16*)(p + 33554432);
    u16*   mb   = hao;                    // spans hao + qkv (33,554,432 B)
    u16*   h2   = wTa;                    // spans wTa + wTap (8,388,608 B)
    float* x1   = out;                    // residual stream lives in d_out

    const dim3 tb(32, 8);
    tcvt_kernel<<<dim3(3072 / 32, 1024 / 32), tb, 0, stream>>>(w_attn, wTa, 1024, 3072);
    tcvt_kernel<<<dim3(1024 / 32, 1024 / 32), tb, 0, stream>>>(w_ap, wTap, 1024, 1024);
    tcvt_kernel<<<dim3(4096 / 32, 1024 / 32), tb, 0, stream>>>(w_fc, wTfc, 1024, 4096);
    tcvt_kernel<<<dim3(1024 / 32, 4096 / 32), tb, 0, stream>>>(w_fp, wTfp, 4096, 1024);

    ln_kernel<<<R, 256, 0, stream>>>(x, ln1_g, ln1_b, hao);
    gemm_bt<128, 0><<<dim3(32, 24), 256, 0, stream>>>(hao, wTa, b_attn, nullptr, qkv, R, 3072, 1024);
    attn_kernel<<<dim3(16, 32), 256, 0, stream>>>(qkv, hao);
    gemm_bt<64, 2><<<dim3(64, 8), 256, 0, stream>>>(hao, wTap, b_ap, x, x1, R, 1024, 1024);
    ln_kernel<<<R, 256, 0, stream>>>(x1, ln2_g, ln2_b, h2);
    gemm_bt<128, 1><<<dim3(32, 32), 256, 0, stream>>>(h2, wTfc, b_fc, nullptr, mb, R, 4096, 1024);
    gemm_bt<64, 2><<<dim3(64, 8), 256, 0, stream>>>(mb, wTfp, b_fp, x1, out, R, 1024, 4096);
}

// Round 7
// 292.024 us; speedup vs baseline: 17.1495x; 1.0715x over previous
//
#include <hip/hip_runtime.h>
#include <hip/hip_bf16.h>
#include <math.h>

typedef __bf16 bf16_t;
typedef bf16_t bf16x8 __attribute__((ext_vector_type(8)));
typedef float f32x4 __attribute__((ext_vector_type(4)));
typedef unsigned short u16;
typedef u16 ushort8 __attribute__((ext_vector_type(8)));

static __device__ __forceinline__ u16 f2bf(float f) {
    unsigned u = __builtin_bit_cast(unsigned, f);
    u += 0x7FFFu + ((u >> 16) & 1u);
    return (u16)(u >> 16);
}

// ---------------- LayerNorm: fp32 in -> bf16 out, one block per row (D=1024) --
__global__ __launch_bounds__(256) void ln_kernel(
    const float* __restrict__ x, const float* __restrict__ g,
    const float* __restrict__ be, u16* __restrict__ out)
{
    const int row = blockIdx.x;
    const int tid = threadIdx.x;
    const float4 v = ((const float4*)(x + (long)row * 1024))[tid];
    float s = v.x + v.y + v.z + v.w;
#pragma unroll
    for (int d = 32; d >= 1; d >>= 1) s += __shfl_xor(s, d);
    __shared__ float r1[4], r2[4];
    if ((tid & 63) == 0) r1[tid >> 6] = s;
    __syncthreads();
    const float mean = (r1[0] + r1[1] + r1[2] + r1[3]) * (1.0f / 1024.0f);
    const float dx = v.x - mean, dy = v.y - mean, dz = v.z - mean, dw = v.w - mean;
    float sq = dx * dx + dy * dy + dz * dz + dw * dw;
#pragma unroll
    for (int d = 32; d >= 1; d >>= 1) sq += __shfl_xor(sq, d);
    if ((tid & 63) == 0) r2[tid >> 6] = sq;
    __syncthreads();
    const float var = (r2[0] + r2[1] + r2[2] + r2[3]) * (1.0f / 1024.0f);
    const float rstd = rsqrtf(var + 1e-5f);
    const float4 gg = ((const float4*)g)[tid];
    const float4 bb = ((const float4*)be)[tid];
    ushort4 o;
    o.x = f2bf(dx * rstd * gg.x + bb.x);
    o.y = f2bf(dy * rstd * gg.y + bb.y);
    o.z = f2bf(dz * rstd * gg.z + bb.z);
    o.w = f2bf(dw * rstd * gg.w + bb.w);
    *(ushort4*)&out[(long)row * 1024 + tid * 4] = o;
}

// ---------------- Transpose + cvt: fp32 [R][C] -> bf16 [C][R] ----------------
__global__ __launch_bounds__(256) void tcvt_kernel(
    const float* __restrict__ in, u16* __restrict__ outT, int R, int C)
{
    __shared__ float tile[32][33];
    const int tx = threadIdx.x, ty = threadIdx.y; // 32 x 8
    const int c0 = blockIdx.x * 32, r0 = blockIdx.y * 32;
#pragma unroll
    for (int i = 0; i < 4; ++i)
        tile[ty + i * 8][tx] = in[(long)(r0 + ty + i * 8) * C + c0 + tx];
    __syncthreads();
#pragma unroll
    for (int i = 0; i < 4; ++i)
        outT[(long)(c0 + ty + i * 8) * R + r0 + tx] = f2bf(tile[tx][ty + i * 8]);
}

// ---------------- GEMM body: C[M,N] = A[M,K] @ Bt[N,K]^T + bias --------------
// Depth-2 pipeline (T3/T4 minimum): LDS double-buffered, raw s_barrier,
// counted vmcnt (never 0 in steady state) so next-tile global_load_lds stays
// in flight across the whole compute phase.
// EPI 0: store bf16. EPI 1: sigmoid-GELU -> bf16. EPI 2: += fp32 resid -> fp32.
template <int BM, int EPI>
static __device__ __forceinline__ void gemm_body(
    const u16* __restrict__ A, const u16* __restrict__ Bt,
    const float* __restrict__ bias, const float* __restrict__ resid,
    void* __restrict__ C, int M, int N, int K)
{
    constexpr int WN = (BM == 128) ? 2 : 4;   // waves along N
    constexpr int MR = 4;                     // m-frags per wave
    constexpr int NR = 128 / WN / 16;         // n-frags per wave (4 or 2)
    constexpr int AI = BM / 64;               // A stage instrs per wave
    constexpr int LPW = AI + 2;               // loads/wave/tile (A + B)
    __shared__ __align__(16) u16 As[2][BM * 32];
    __shared__ __align__(16) u16 Bs[2][128 * 32];
    const int tid = threadIdx.x;
    const int lane = tid & 63;
    const int w = tid >> 6;
    const int wm = w / WN, wn = w % WN;
    const int bm = blockIdx.x, bn = blockIdx.y;
    f32x4 acc[MR][NR] = {};

    const u16* Ablk = A + (long)bm * BM * K;
    const u16* Bblk = Bt + (long)bn * 128 * K;
    const int nt = K >> 5;

    auto stage = [&](int buf, int kb) {
#pragma unroll
        for (int i = 0; i < AI; ++i) {
            const int o = (w * AI + i) * 512 + lane * 8;
            const int row = o >> 5, kk = o & 31;
            __builtin_amdgcn_global_load_lds(
                (const __attribute__((address_space(1))) void*)(Ablk + (long)row * K + kb + kk),
                (__attribute__((address_space(3))) void*)(&As[buf][(w * AI + i) * 512]),
                16, 0, 0);
        }
#pragma unroll
        for (int i = 0; i < 2; ++i) {
            const int o = (w * 2 + i) * 512 + lane * 8;
            const int row = o >> 5, kk = o & 31;
            __builtin_amdgcn_global_load_lds(
                (const __attribute__((address_space(1))) void*)(Bblk + (long)row * K + kb + kk),
                (__attribute__((address_space(3))) void*)(&Bs[buf][(w * 2 + i) * 512]),
                16, 0, 0);
        }
    };

    stage(0, 0);
    for (int t = 0; t < nt; ++t) {
        const int cur = t & 1;
        if (t + 1 < nt) {
            stage(cur ^ 1, (t + 1) << 5);
            asm volatile("s_waitcnt vmcnt(%0)" :: "i"(LPW) : "memory");
        } else {
            asm volatile("s_waitcnt vmcnt(0)" ::: "memory");
        }
        __builtin_amdgcn_s_barrier();          // buf[cur] staged by all waves
        asm volatile("" ::: "memory");         // no LDS reads hoist above this

        bf16x8 af[MR], bfr[NR];
#pragma unroll
        for (int m = 0; m < MR; ++m)
            af[m] = *(const bf16x8*)&As[cur][(wm * MR * 16 + m * 16 + (lane & 15)) * 32 + (lane >> 4) * 8];
#pragma unroll
        for (int n = 0; n < NR; ++n)
            bfr[n] = *(const bf16x8*)&Bs[cur][(wn * NR * 16 + n * 16 + (lane & 15)) * 32 + (lane >> 4) * 8];
#pragma unroll
        for (int m = 0; m < MR; ++m)
#pragma unroll
            for (int n = 0; n < NR; ++n)
                acc[m][n] = __builtin_amdgcn_mfma_f32_16x16x32_bf16(af[m], bfr[n], acc[m][n], 0, 0, 0);

        if (t + 1 < nt) {
            asm volatile("" ::: "memory");     // no LDS reads sink below
            __builtin_amdgcn_s_barrier();      // all reads of buf[cur] done
        }
    }

    const int rowBase = bm * BM + wm * MR * 16;
    const int colBase = bn * 128 + wn * NR * 16;
#pragma unroll
    for (int n = 0; n < NR; ++n) {
        const int col = colBase + n * 16 + (lane & 15);
        const float bv = bias[col];
#pragma unroll
        for (int m = 0; m < MR; ++m) {
#pragma unroll
            for (int r = 0; r < 4; ++r) {
                const int row = rowBase + m * 16 + (lane >> 4) * 4 + r;
                float v = acc[m][n][r] + bv;
                if constexpr (EPI == 1) {
                    // sigmoid-form GELU (|err| vs erf-GELU ~1e-3 << bf16 noise)
                    const float u = v + 0.044715f * v * v * v;
                    v = v / (1.0f + __expf(-1.5957691216057308f * u));
                }
                if constexpr (EPI == 2) {
                    ((float*)C)[(long)row * N + col] = v + resid[(long)row * N + col];
                } else {
                    ((u16*)C)[(long)row * N + col] = f2bf(v);
                }
            }
        }
    }
}

// Distinctly-named wrappers so rocprof separates the four GEMMs.
__global__ __launch_bounds__(256) void gemm_qkv(
    const u16* A, const u16* Bt, const float* bias, const float* resid,
    void* C, int M, int N, int K) { gemm_body<128, 0>(A, Bt, bias, resid, C, M, N, K); }
__global__ __launch_bounds__(256) void gemm_fc(
    const u16* A, const u16* Bt, const float* bias, const float* resid,
    void* C, int M, int N, int K) { gemm_body<128, 1>(A, Bt, bias, resid, C, M, N, K); }
__global__ __launch_bounds__(256) void gemm_ap(
    const u16* A, const u16* Bt, const float* bias, const float* resid,
    void* C, int M, int N, int K) { gemm_body<64, 2>(A, Bt, bias, resid, C, M, N, K); }
__global__ __launch_bounds__(256) void gemm_fp(
    const u16* A, const u16* Bt, const float* bias, const float* resid,
    void* C, int M, int N, int K) { gemm_body<64, 2>(A, Bt, bias, resid, C, M, N, K); }

// ---------------- Flash attention v4 (causal), paired q-tiles, dbuf K/V ------
// XOR-swizzled V^T LDS layout (conflict-free); see round-5 derivation.
__global__ __launch_bounds__(256) void attn_kernel(
    const u16* __restrict__ qkv, u16* __restrict__ outb)
{
    const int S = 2048;
    const int ipair = blockIdx.x;        // 0..15
    const int bh = blockIdx.y;           // b*16 + h
    const int b = bh >> 4, h = bh & 15;
    const int tid = threadIdx.x, lane = tid & 63, w = tid >> 6;
    __shared__ __align__(16) u16 Ks[2][64 * 72];     // [kv][hd], +8 pad
    __shared__ __align__(16) u16 Vs[2][64 * 72];     // [hd][kv^swz], +8 pad
    __shared__ __align__(16) u16 Ps[4][16 * 72];     // per-wave P [q][kv], +8 pad

    const long base = (long)b * S * 3072;
    const int rstage = tid >> 3;         // 0..31 (staging row within half-tile)
    const int cg = (tid & 7) * 8;        // staging col group
    const int sw = cg;                   // V swizzle bits
    const u16* kbase = qkv + base + 1024 + h * 64 + cg;
    const u16* vbase = qkv + base + 2048 + h * 64 + cg;

    for (int half = 0; half < 2; ++half) {
        const int qt = half ? 31 - ipair : ipair;
        const int q0 = qt * 64;

        bf16x8 qf[2];
        {
            const int qrow = q0 + w * 16 + (lane & 15);
#pragma unroll
            for (int c = 0; c < 2; ++c)
                qf[c] = *(const bf16x8*)&qkv[base + (long)qrow * 3072 + h * 64 + c * 32 + (lane >> 4) * 8];
        }

        f32x4 Of[4] = {};
        float mrow[4], lrow[4];
#pragma unroll
        for (int r = 0; r < 4; ++r) { mrow[r] = -1e30f; lrow[r] = 0.0f; }

        ushort8 kr[2], vr[2];
#pragma unroll
        for (int it = 0; it < 2; ++it) {
            const long ro = (long)(it * 32 + rstage) * 3072;
            kr[it] = *(const ushort8*)&kbase[ro];
            vr[it] = *(const ushort8*)&vbase[ro];
        }
        __syncthreads();   // protect buffers from previous half's readers
#pragma unroll
        for (int it = 0; it < 2; ++it) {
            const int r = it * 32 + rstage;
            *(ushort8*)&Ks[0][r * 72 + cg] = kr[it];
#pragma unroll
            for (int j = 0; j < 8; ++j)
                Vs[0][(cg + j) * 72 + (r ^ sw)] = vr[it][j];
        }

        for (int kt = 0; kt <= qt; ++kt) {
            const int cur = kt & 1;
            if (kt < qt) {
#pragma unroll
                for (int it = 0; it < 2; ++it) {
                    const long ro = (long)((kt + 1) * 64 + it * 32 + rstage) * 3072;
                    kr[it] = *(const ushort8*)&kbase[ro];
                    vr[it] = *(const ushort8*)&vbase[ro];
                }
            }
            __syncthreads();   // buf[cur] staged & visible to all waves

            f32x4 Sf[4] = {};
#pragma unroll
            for (int f = 0; f < 4; ++f) {
#pragma unroll
                for (int c = 0; c < 2; ++c) {
                    const bf16x8 kf = *(const bf16x8*)&Ks[cur][(f * 16 + (lane & 15)) * 72 + c * 32 + (lane >> 4) * 8];
                    Sf[f] = __builtin_amdgcn_mfma_f32_16x16x32_bf16(qf[c], kf, Sf[f], 0, 0, 0);
                }
            }
#pragma unroll
            for (int f = 0; f < 4; ++f)
#pragma unroll
                for (int r = 0; r < 4; ++r)
                    Sf[f][r] *= 0.125f;
            if (kt == qt) {
#pragma unroll
                for (int f = 0; f < 4; ++f) {
                    const int kvc = f * 16 + (lane & 15);
#pragma unroll
                    for (int r = 0; r < 4; ++r) {
                        const int qr = w * 16 + (lane >> 4) * 4 + r;
                        if (kvc > qr) Sf[f][r] = -1e30f;
                    }
                }
            }
            float mnew[4], sc[4];
#pragma unroll
            for (int r = 0; r < 4; ++r) {
                float mx = fmaxf(fmaxf(Sf[0][r], Sf[1][r]), fmaxf(Sf[2][r], Sf[3][r]));
#pragma unroll
                for (int d = 1; d < 16; d <<= 1) mx = fmaxf(mx, __shfl_xor(mx, d));
                mnew[r] = fmaxf(mrow[r], mx);
                sc[r] = __expf(mrow[r] - mnew[r]);
                mrow[r] = mnew[r];
            }
#pragma unroll
            for (int f = 0; f < 4; ++f)
#pragma unroll
                for (int r = 0; r < 4; ++r)
                    Sf[f][r] = __expf(Sf[f][r] - mnew[r]);
#pragma unroll
            for (int r = 0; r < 4; ++r) {
                float s = Sf[0][r] + Sf[1][r] + Sf[2][r] + Sf[3][r];
#pragma unroll
                for (int d = 1; d < 16; d <<= 1) s += __shfl_xor(s, d);
                lrow[r] = lrow[r] * sc[r] + s;
            }
#pragma unroll
            for (int f = 0; f < 4; ++f)
#pragma unroll
                for (int r = 0; r < 4; ++r)
                    Of[f][r] *= sc[r];
#pragma unroll
            for (int f = 0; f < 4; ++f)
#pragma unroll
                for (int r = 0; r < 4; ++r)
                    Ps[w][((lane >> 4) * 4 + r) * 72 + f * 16 + (lane & 15)] = f2bf(Sf[f][r]);
#pragma unroll
            for (int f = 0; f < 4; ++f) {
                const int hd = f * 16 + (lane & 15);
#pragma unroll
                for (int c = 0; c < 2; ++c) {
                    const int k0 = c * 32 + (lane >> 4) * 8;
                    const bf16x8 pa = *(const bf16x8*)&Ps[w][(lane & 15) * 72 + k0];
                    const bf16x8 vb = *(const bf16x8*)&Vs[cur][hd * 72 + (k0 ^ (hd & 56))];
                    Of[f] = __builtin_amdgcn_mfma_f32_16x16x32_bf16(pa, vb, Of[f], 0, 0, 0);
                }
            }
            if (kt < qt) {
#pragma unroll
                for (int it = 0; it < 2; ++it) {
                    const int r = it * 32 + rstage;
                    *(ushort8*)&Ks[cur ^ 1][r * 72 + cg] = kr[it];
#pragma unroll
                    for (int j = 0; j < 8; ++j)
                        Vs[cur ^ 1][(cg + j) * 72 + (r ^ sw)] = vr[it][j];
                }
            }
        }

        float inv[4];
#pragma unroll
        for (int r = 0; r < 4; ++r) inv[r] = 1.0f / lrow[r];
#pragma unroll
        for (int f = 0; f < 4; ++f) {
            const int col = h * 64 + f * 16 + (lane & 15);
#pragma unroll
            for (int r = 0; r < 4; ++r) {
                const int qrow = q0 + w * 16 + (lane >> 4) * 4 + r;
                outb[((long)b * S + qrow) * 1024 + col] = f2bf(Of[f][r] * inv[r]);
            }
        }
    }
}

// -----------------------------------------------------------------------------
// Workspace plan (56 MiB total; x1 lives in d_out):
//   [0        , 6291456 )  wTa   bf16 [3072][1024]   (dead after qkv GEMM)
//   [6291456  , 8388608 )  wTap  bf16 [1024][1024]   (dead after attn-proj)
//   [8388608  , 16777216)  wTfc  bf16 [4096][1024]
//   [16777216 , 25165824)  wTfp  bf16 [1024][4096]
//   [25165824 , 33554432)  hao   bf16 [4096][1024]   h (ln1 out), then ao (attn out)
//   [33554432 , 58720256)  qkv   bf16 [4096][3072]
//   mb = [25165824, 58720256) bf16 [4096][4096]      (over hao∪qkv, both dead)
//   h2 = [0, 8388608)       bf16 [4096][1024]        (over wTa∪wTap, both dead)
extern "C" void kernel_launch(void* const* d_in, const int* in_sizes, int n_in,
                              void* d_out, int out_size, void* d_ws, size_t ws_size,
                              hipStream_t stream) {
    const float* x      = (const float*)d_in[0];
    const float* ln1_g  = (const float*)d_in[1];
    const float* ln1_b  = (const float*)d_in[2];
    const float* w_attn = (const float*)d_in[3];
    const float* b_attn = (const float*)d_in[4];
    const float* w_ap   = (const float*)d_in[5];
    const float* b_ap   = (const float*)d_in[6];
    const float* ln2_g  = (const float*)d_in[7];
    const float* ln2_b  = (const float*)d_in[8];
    const float* w_fc   = (const float*)d_in[9];
    const float* b_fc   = (const float*)d_in[10];
    const float* w_fp   = (const float*)d_in[11];
    const float* b_fp   = (const float*)d_in[12];
    float* out = (float*)d_out;

    const int R = 4096; // B*S
    char* p = (char*)d_ws;
    u16*   wTa  = (u16*)(p);
    u16*   wTap = (u16*)(p + 6291456);
    u16*   wTfc = (u16*)(p + 8388608);
    u16*   wTfp = (u16*)(p + 16777216);
    u16*   hao  = (u16*)(p + 25165824);   // h, later reused as ao
    u16*   qkv  = (u16*)(p + 33554432);
    u16*   mb   = hao;                    // spans hao + qkv (33,554,432 B)
    u16*   h2   = wTa;                    // spans wTa + wTap (8,388,608 B)
    float* x1   = out;                    // residual stream lives in d_out

    const dim3 tb(32, 8);
    tcvt_kernel<<<dim3(3072 / 32, 1024 / 32), tb, 0, stream>>>(w_attn, wTa, 1024, 3072);
    tcvt_kernel<<<dim3(1024 / 32, 1024 / 32), tb, 0, stream>>>(w_ap, wTap, 1024, 1024);
    tcvt_kernel<<<dim3(4096 / 32, 1024 / 32), tb, 0, stream>>>(w_fc, wTfc, 1024, 4096);
    tcvt_kernel<<<dim3(1024 / 32, 4096 / 32), tb, 0, stream>>>(w_fp, wTfp, 4096, 1024);

    ln_kernel<<<R, 256, 0, stream>>>(x, ln1_g, ln1_b, hao);
    gemm_qkv<<<dim3(32, 24), 256, 0, stream>>>(hao, wTa, b_attn, nullptr, qkv, R, 3072, 1024);
    attn_kernel<<<dim3(16, 32), 256, 0, stream>>>(qkv, hao);
    gemm_ap<<<dim3(64, 8), 256, 0, stream>>>(hao, wTap, b_ap, x, x1, R, 1024, 1024);
    ln_kernel<<<R, 256, 0, stream>>>(x1, ln2_g, ln2_b, h2);
    gemm_fc<<<dim3(32, 32), 256, 0, stream>>>(h2, wTfc, b_fc, nullptr, mb, R, 4096, 1024);
    gemm_fp<<<dim3(64, 8), 256, 0, stream>>>(mb, wTfp, b_fp, x1, out, R, 1024, 4096);
}

// Round 8
// 271.476 us; speedup vs baseline: 18.4476x; 1.0757x over previous
//
#include <hip/hip_runtime.h>
#include <hip/hip_bf16.h>
#include <math.h>

typedef __bf16 bf16_t;
typedef bf16_t bf16x8 __attribute__((ext_vector_type(8)));
typedef float f32x4 __attribute__((ext_vector_type(4)));
typedef unsigned short u16;
typedef u16 ushort8 __attribute__((ext_vector_type(8)));

static __device__ __forceinline__ u16 f2bf(float f) {
    unsigned u = __builtin_bit_cast(unsigned, f);
    u += 0x7FFFu + ((u >> 16) & 1u);
    return (u16)(u >> 16);
}

// ---------------- LayerNorm: fp32 in -> bf16 out, one block per row (D=1024) --
__global__ __launch_bounds__(256) void ln_kernel(
    const float* __restrict__ x, const float* __restrict__ g,
    const float* __restrict__ be, u16* __restrict__ out)
{
    const int row = blockIdx.x;
    const int tid = threadIdx.x;
    const float4 v = ((const float4*)(x + (long)row * 1024))[tid];
    float s = v.x + v.y + v.z + v.w;
#pragma unroll
    for (int d = 32; d >= 1; d >>= 1) s += __shfl_xor(s, d);
    __shared__ float r1[4], r2[4];
    if ((tid & 63) == 0) r1[tid >> 6] = s;
    __syncthreads();
    const float mean = (r1[0] + r1[1] + r1[2] + r1[3]) * (1.0f / 1024.0f);
    const float dx = v.x - mean, dy = v.y - mean, dz = v.z - mean, dw = v.w - mean;
    float sq = dx * dx + dy * dy + dz * dz + dw * dw;
#pragma unroll
    for (int d = 32; d >= 1; d >>= 1) sq += __shfl_xor(sq, d);
    if ((tid & 63) == 0) r2[tid >> 6] = sq;
    __syncthreads();
    const float var = (r2[0] + r2[1] + r2[2] + r2[3]) * (1.0f / 1024.0f);
    const float rstd = rsqrtf(var + 1e-5f);
    const float4 gg = ((const float4*)g)[tid];
    const float4 bb = ((const float4*)be)[tid];
    ushort4 o;
    o.x = f2bf(dx * rstd * gg.x + bb.x);
    o.y = f2bf(dy * rstd * gg.y + bb.y);
    o.z = f2bf(dz * rstd * gg.z + bb.z);
    o.w = f2bf(dw * rstd * gg.w + bb.w);
    *(ushort4*)&out[(long)row * 1024 + tid * 4] = o;
}

// ---------------- Transpose + cvt: fp32 [R][C] -> bf16 [C][R] ----------------
__global__ __launch_bounds__(256) void tcvt_kernel(
    const float* __restrict__ in, u16* __restrict__ outT, int R, int C)
{
    __shared__ float tile[32][33];
    const int tx = threadIdx.x, ty = threadIdx.y; // 32 x 8
    const int c0 = blockIdx.x * 32, r0 = blockIdx.y * 32;
#pragma unroll
    for (int i = 0; i < 4; ++i)
        tile[ty + i * 8][tx] = in[(long)(r0 + ty + i * 8) * C + c0 + tx];
    __syncthreads();
#pragma unroll
    for (int i = 0; i < 4; ++i)
        outT[(long)(c0 + ty + i * 8) * R + r0 + tx] = f2bf(tile[tx][ty + i * 8]);
}

// ---------------- GEMM body: C[M,N] = A[M,K] @ Bt[N,K]^T + bias --------------
// Depth-2 pipeline: LDS double-buffered, raw s_barrier, counted vmcnt.
// EPI 0: bf16. EPI 1: sigmoid-GELU -> bf16. EPI 2: += fp32 resid -> fp32.
// EPI 3: bf16 with cols<1024 scaled by 0.125 (q-prescale folded into qkv GEMM).
template <int BM, int EPI>
static __device__ __forceinline__ void gemm_body(
    const u16* __restrict__ A, const u16* __restrict__ Bt,
    const float* __restrict__ bias, const float* __restrict__ resid,
    void* __restrict__ C, int M, int N, int K)
{
    constexpr int WN = (BM == 128) ? 2 : 4;   // waves along N
    constexpr int MR = 4;                     // m-frags per wave
    constexpr int NR = 128 / WN / 16;         // n-frags per wave (4 or 2)
    constexpr int AI = BM / 64;               // A stage instrs per wave
    constexpr int LPW = AI + 2;               // loads/wave/tile (A + B)
    __shared__ __align__(16) u16 As[2][BM * 32];
    __shared__ __align__(16) u16 Bs[2][128 * 32];
    const int tid = threadIdx.x;
    const int lane = tid & 63;
    const int w = tid >> 6;
    const int wm = w / WN, wn = w % WN;
    const int bm = blockIdx.x, bn = blockIdx.y;
    f32x4 acc[MR][NR] = {};

    const u16* Ablk = A + (long)bm * BM * K;
    const u16* Bblk = Bt + (long)bn * 128 * K;
    const int nt = K >> 5;

    auto stage = [&](int buf, int kb) {
#pragma unroll
        for (int i = 0; i < AI; ++i) {
            const int o = (w * AI + i) * 512 + lane * 8;
            const int row = o >> 5, kk = o & 31;
            __builtin_amdgcn_global_load_lds(
                (const __attribute__((address_space(1))) void*)(Ablk + (long)row * K + kb + kk),
                (__attribute__((address_space(3))) void*)(&As[buf][(w * AI + i) * 512]),
                16, 0, 0);
        }
#pragma unroll
        for (int i = 0; i < 2; ++i) {
            const int o = (w * 2 + i) * 512 + lane * 8;
            const int row = o >> 5, kk = o & 31;
            __builtin_amdgcn_global_load_lds(
                (const __attribute__((address_space(1))) void*)(Bblk + (long)row * K + kb + kk),
                (__attribute__((address_space(3))) void*)(&Bs[buf][(w * 2 + i) * 512]),
                16, 0, 0);
        }
    };

    stage(0, 0);
    for (int t = 0; t < nt; ++t) {
        const int cur = t & 1;
        if (t + 1 < nt) {
            stage(cur ^ 1, (t + 1) << 5);
            asm volatile("s_waitcnt vmcnt(%0)" :: "i"(LPW) : "memory");
        } else {
            asm volatile("s_waitcnt vmcnt(0)" ::: "memory");
        }
        __builtin_amdgcn_s_barrier();          // buf[cur] staged by all waves
        asm volatile("" ::: "memory");         // no LDS reads hoist above this

        bf16x8 af[MR], bfr[NR];
#pragma unroll
        for (int m = 0; m < MR; ++m)
            af[m] = *(const bf16x8*)&As[cur][(wm * MR * 16 + m * 16 + (lane & 15)) * 32 + (lane >> 4) * 8];
#pragma unroll
        for (int n = 0; n < NR; ++n)
            bfr[n] = *(const bf16x8*)&Bs[cur][(wn * NR * 16 + n * 16 + (lane & 15)) * 32 + (lane >> 4) * 8];
#pragma unroll
        for (int m = 0; m < MR; ++m)
#pragma unroll
            for (int n = 0; n < NR; ++n)
                acc[m][n] = __builtin_amdgcn_mfma_f32_16x16x32_bf16(af[m], bfr[n], acc[m][n], 0, 0, 0);

        if (t + 1 < nt) {
            asm volatile("" ::: "memory");     // no LDS reads sink below
            __builtin_amdgcn_s_barrier();      // all reads of buf[cur] done
        }
    }

    const int rowBase = bm * BM + wm * MR * 16;
    const int colBase = bn * 128 + wn * NR * 16;
#pragma unroll
    for (int n = 0; n < NR; ++n) {
        const int col = colBase + n * 16 + (lane & 15);
        const float bv = bias[col];
#pragma unroll
        for (int m = 0; m < MR; ++m) {
#pragma unroll
            for (int r = 0; r < 4; ++r) {
                const int row = rowBase + m * 16 + (lane >> 4) * 4 + r;
                float v = acc[m][n][r] + bv;
                if constexpr (EPI == 1) {
                    // sigmoid-form GELU (|err| vs erf-GELU ~1e-3 << bf16 noise)
                    const float u = v + 0.044715f * v * v * v;
                    v = v / (1.0f + __expf(-1.5957691216057308f * u));
                }
                if constexpr (EPI == 3) {
                    if (col < 1024) v *= 0.125f;   // q-prescale (exact)
                }
                if constexpr (EPI == 2) {
                    ((float*)C)[(long)row * N + col] = v + resid[(long)row * N + col];
                } else {
                    ((u16*)C)[(long)row * N + col] = f2bf(v);
                }
            }
        }
    }
}

__global__ __launch_bounds__(256) void gemm_qkv(
    const u16* A, const u16* Bt, const float* bias, const float* resid,
    void* C, int M, int N, int K) { gemm_body<128, 3>(A, Bt, bias, resid, C, M, N, K); }
__global__ __launch_bounds__(256) void gemm_fc(
    const u16* A, const u16* Bt, const float* bias, const float* resid,
    void* C, int M, int N, int K) { gemm_body<128, 1>(A, Bt, bias, resid, C, M, N, K); }
__global__ __launch_bounds__(256) void gemm_ap(
    const u16* A, const u16* Bt, const float* bias, const float* resid,
    void* C, int M, int N, int K) { gemm_body<64, 2>(A, Bt, bias, resid, C, M, N, K); }
__global__ __launch_bounds__(256) void gemm_fp(
    const u16* A, const u16* Bt, const float* bias, const float* resid,
    void* C, int M, int N, int K) { gemm_body<64, 2>(A, Bt, bias, resid, C, M, N, K); }

// ---------------- Flash attention v5 (causal): swapped QK^T + lane-local SM --
// qkv: bf16 [B*S][3072] (q already prescaled by 0.125 in gemm_qkv).
// S^T = mfma(K, Q): lane holds S[q = lane&15][kv = f*16 + (lane>>4)*4 + r]
// -> softmax per lane (own-16 reduce + 2 shfl_xor), scalar m/l per lane,
//    defer-max rescale (skip when __all(pmax <= m+8)), P packed to ds_write_b64.
// PV unchanged: pa b128 from Ps rows (lane&15), vb XOR-swizzled V^T.
__global__ __launch_bounds__(256) void attn_kernel(
    const u16* __restrict__ qkv, u16* __restrict__ outb)
{
    const int S = 2048;
    const int ipair = blockIdx.x;        // 0..15
    const int bh = blockIdx.y;           // b*16 + h
    const int b = bh >> 4, h = bh & 15;
    const int tid = threadIdx.x, lane = tid & 63, w = tid >> 6;
    __shared__ __align__(16) u16 Ks[2][64 * 72];     // [kv][hd], +8 pad
    __shared__ __align__(16) u16 Vs[2][64 * 72];     // [hd][kv^swz], +8 pad
    __shared__ __align__(16) u16 Ps[4][16 * 72];     // per-wave P [q][kv], +8 pad

    const long base = (long)b * S * 3072;
    const int rstage = tid >> 3;         // 0..31 (staging row within half-tile)
    const int cg = (tid & 7) * 8;        // staging col group
    const int sw = cg;                   // V swizzle bits
    const u16* kbase = qkv + base + 1024 + h * 64 + cg;
    const u16* vbase = qkv + base + 2048 + h * 64 + cg;

    for (int half = 0; half < 2; ++half) {
        const int qt = half ? 31 - ipair : ipair;
        const int q0 = qt * 64;

        bf16x8 qf[2];
        {
            const int qrow = q0 + w * 16 + (lane & 15);
#pragma unroll
            for (int c = 0; c < 2; ++c)
                qf[c] = *(const bf16x8*)&qkv[base + (long)qrow * 3072 + h * 64 + c * 32 + (lane >> 4) * 8];
        }

        f32x4 Of[4] = {};
        float m = -1e30f, l = 0.0f;      // scalar state for q-row (lane&15)

        ushort8 kr[2], vr[2];
#pragma unroll
        for (int it = 0; it < 2; ++it) {
            const long ro = (long)(it * 32 + rstage) * 3072;
            kr[it] = *(const ushort8*)&kbase[ro];
            vr[it] = *(const ushort8*)&vbase[ro];
        }
        __syncthreads();   // protect buffers from previous half's readers
#pragma unroll
        for (int it = 0; it < 2; ++it) {
            const int r = it * 32 + rstage;
            *(ushort8*)&Ks[0][r * 72 + cg] = kr[it];
#pragma unroll
            for (int j = 0; j < 8; ++j)
                Vs[0][(cg + j) * 72 + (r ^ sw)] = vr[it][j];
        }

        for (int kt = 0; kt <= qt; ++kt) {
            const int cur = kt & 1;
            if (kt < qt) {
#pragma unroll
                for (int it = 0; it < 2; ++it) {
                    const long ro = (long)((kt + 1) * 64 + it * 32 + rstage) * 3072;
                    kr[it] = *(const ushort8*)&kbase[ro];
                    vr[it] = *(const ushort8*)&vbase[ro];
                }
            }
            __syncthreads();   // buf[cur] staged & visible to all waves

            // S^T = K @ Q^T  (swapped): row = kv, col = q
            f32x4 Sf[4] = {};
#pragma unroll
            for (int f = 0; f < 4; ++f) {
#pragma unroll
                for (int c = 0; c < 2; ++c) {
                    const bf16x8 kf = *(const bf16x8*)&Ks[cur][(f * 16 + (lane & 15)) * 72 + c * 32 + (lane >> 4) * 8];
                    Sf[f] = __builtin_amdgcn_mfma_f32_16x16x32_bf16(kf, qf[c], Sf[f], 0, 0, 0);
                }
            }
            // causal mask (diagonal tile only): kv_local > q_local
            if (kt == qt) {
                const int ql = w * 16 + (lane & 15);
#pragma unroll
                for (int f = 0; f < 4; ++f) {
#pragma unroll
                    for (int r = 0; r < 4; ++r) {
                        const int kvl = f * 16 + ((lane >> 4) << 2) + r;
                        if (kvl > ql) Sf[f][r] = -1e30f;
                    }
                }
            }
            // lane-local online softmax with defer-max
            float pmax = Sf[0][0];
#pragma unroll
            for (int f = 0; f < 4; ++f)
#pragma unroll
                for (int r = 0; r < 4; ++r) pmax = fmaxf(pmax, Sf[f][r]);
            if (!__all(pmax <= m + 8.0f)) {
                float pm = pmax;
                pm = fmaxf(pm, __shfl_xor(pm, 16));
                pm = fmaxf(pm, __shfl_xor(pm, 32));
                const float mnew = fmaxf(m, pm);
                const float sc = __expf(m - mnew);
                m = mnew;
                l *= sc;
                float sco[4];
#pragma unroll
                for (int r = 0; r < 4; ++r)
                    sco[r] = __shfl(sc, ((lane >> 4) << 2) + r);
#pragma unroll
                for (int f = 0; f < 4; ++f)
#pragma unroll
                    for (int r = 0; r < 4; ++r) Of[f][r] *= sco[r];
            }
            float osum = 0.0f;
#pragma unroll
            for (int f = 0; f < 4; ++f)
#pragma unroll
                for (int r = 0; r < 4; ++r) {
                    const float e = __expf(Sf[f][r] - m);
                    Sf[f][r] = e;
                    osum += e;
                }
            l += osum;
            // P -> LDS: pack 4 consecutive kv (r=0..3) into one b64 write
#pragma unroll
            for (int f = 0; f < 4; ++f) {
                const unsigned lo = (unsigned)f2bf(Sf[f][0]) | ((unsigned)f2bf(Sf[f][1]) << 16);
                const unsigned hi = (unsigned)f2bf(Sf[f][2]) | ((unsigned)f2bf(Sf[f][3]) << 16);
                uint2 pk; pk.x = lo; pk.y = hi;
                *(uint2*)&Ps[w][(lane & 15) * 72 + f * 16 + ((lane >> 4) << 2)] = pk;
            }
            // O += P @ V
#pragma unroll
            for (int f = 0; f < 4; ++f) {
                const int hd = f * 16 + (lane & 15);
#pragma unroll
                for (int c = 0; c < 2; ++c) {
                    const int k0 = c * 32 + (lane >> 4) * 8;
                    const bf16x8 pa = *(const bf16x8*)&Ps[w][(lane & 15) * 72 + k0];
                    const bf16x8 vb = *(const bf16x8*)&Vs[cur][hd * 72 + (k0 ^ (hd & 56))];
                    Of[f] = __builtin_amdgcn_mfma_f32_16x16x32_bf16(pa, vb, Of[f], 0, 0, 0);
                }
            }
            if (kt < qt) {
#pragma unroll
                for (int it = 0; it < 2; ++it) {
                    const int r = it * 32 + rstage;
                    *(ushort8*)&Ks[cur ^ 1][r * 72 + cg] = kr[it];
#pragma unroll
                    for (int j = 0; j < 8; ++j)
                        Vs[cur ^ 1][(cg + j) * 72 + (r ^ sw)] = vr[it][j];
                }
            }
        }

        // reduce l across the 4 kv-copies of each q-row, broadcast to O rows
        float lt = l;
        lt += __shfl_xor(lt, 16);
        lt += __shfl_xor(lt, 32);
        const float linv = 1.0f / lt;
        float inv[4];
#pragma unroll
        for (int r = 0; r < 4; ++r)
            inv[r] = __shfl(linv, ((lane >> 4) << 2) + r);
#pragma unroll
        for (int f = 0; f < 4; ++f) {
            const int col = h * 64 + f * 16 + (lane & 15);
#pragma unroll
            for (int r = 0; r < 4; ++r) {
                const int qrow = q0 + w * 16 + (lane >> 4) * 4 + r;
                outb[((long)b * S + qrow) * 1024 + col] = f2bf(Of[f][r] * inv[r]);
            }
        }
    }
}

// -----------------------------------------------------------------------------
// Workspace plan (56 MiB total; x1 lives in d_out):
//   [0        , 6291456 )  wTa   bf16 [3072][1024]   (dead after qkv GEMM)
//   [6291456  , 8388608 )  wTap  bf16 [1024][1024]   (dead after attn-proj)
//   [8388608  , 16777216)  wTfc  bf16 [4096][1024]
//   [16777216 , 25165824)  wTfp  bf16 [1024][4096]
//   [25165824 , 33554432)  hao   bf16 [4096][1024]   h (ln1 out), then ao (attn out)
//   [33554432 , 58720256)  qkv   bf16 [4096][3072]
//   mb = [25165824, 58720256) bf16 [4096][4096]      (over hao∪qkv, both dead)
//   h2 = [0, 8388608)       bf16 [4096][1024]        (over wTa∪wTap, both dead)
extern "C" void kernel_launch(void* const* d_in, const int* in_sizes, int n_in,
                              void* d_out, int out_size, void* d_ws, size_t ws_size,
                              hipStream_t stream) {
    const float* x      = (const float*)d_in[0];
    const float* ln1_g  = (const float*)d_in[1];
    const float* ln1_b  = (const float*)d_in[2];
    const float* w_attn = (const float*)d_in[3];
    const float* b_attn = (const float*)d_in[4];
    const float* w_ap   = (const float*)d_in[5];
    const float* b_ap   = (const float*)d_in[6];
    const float* ln2_g  = (const float*)d_in[7];
    const float* ln2_b  = (const float*)d_in[8];
    const float* w_fc   = (const float*)d_in[9];
    const float* b_fc   = (const float*)d_in[10];
    const float* w_fp   = (const float*)d_in[11];
    const float* b_fp   = (const float*)d_in[12];
    float* out = (float*)d_out;

    const int R = 4096; // B*S
    char* p = (char*)d_ws;
    u16*   wTa  = (u16*)(p);
    u16*   wTap = (u16*)(p + 6291456);
    u16*   wTfc = (u16*)(p + 8388608);
    u16*   wTfp = (u16*)(p + 16777216);
    u16*   hao  = (u16*)(p + 25165824);   // h, later reused as ao
    u16*   qkv  = (u16*)(p + 33554432);
    u16*   mb   = hao;                    // spans hao + qkv (33,554,432 B)
    u16*   h2   = wTa;                    // spans wTa + wTap (8,388,608 B)
    float* x1   = out;                    // residual stream lives in d_out

    const dim3 tb(32, 8);
    tcvt_kernel<<<dim3(3072 / 32, 1024 / 32), tb, 0, stream>>>(w_attn, wTa, 1024, 3072);
    tcvt_kernel<<<dim3(1024 / 32, 1024 / 32), tb, 0, stream>>>(w_ap, wTap, 1024, 1024);
    tcvt_kernel<<<dim3(4096 / 32, 1024 / 32), tb, 0, stream>>>(w_fc, wTfc, 1024, 4096);
    tcvt_kernel<<<dim3(1024 / 32, 4096 / 32), tb, 0, stream>>>(w_fp, wTfp, 4096, 1024);

    ln_kernel<<<R, 256, 0, stream>>>(x, ln1_g, ln1_b, hao);
    gemm_qkv<<<dim3(32, 24), 256, 0, stream>>>(hao, wTa, b_attn, nullptr, qkv, R, 3072, 1024);
    attn_kernel<<<dim3(16, 32), 256, 0, stream>>>(qkv, hao);
    gemm_ap<<<dim3(64, 8), 256, 0, stream>>>(hao, wTap, b_ap, x, x1, R, 1024, 1024);
    ln_kernel<<<R, 256, 0, stream>>>(x1, ln2_g, ln2_b, h2);
    gemm_fc<<<dim3(32, 32), 256, 0, stream>>>(h2, wTfc, b_fc, nullptr, mb, R, 4096, 1024);
    gemm_fp<<<dim3(64, 8), 256, 0, stream>>>(mb, wTfp, b_fp, x1, out, R, 1024, 4096);
}

// Round 9
// 271.046 us; speedup vs baseline: 18.4768x; 1.0016x over previous
//
#include <hip/hip_runtime.h>
#include <hip/hip_bf16.h>
#include <math.h>

typedef __bf16 bf16_t;
typedef bf16_t bf16x8 __attribute__((ext_vector_type(8)));
typedef float f32x4 __attribute__((ext_vector_type(4)));
typedef unsigned short u16;
typedef u16 ushort8 __attribute__((ext_vector_type(8)));

static __device__ __forceinline__ u16 f2bf(float f) {
    unsigned u = __builtin_bit_cast(unsigned, f);
    u += 0x7FFFu + ((u >> 16) & 1u);
    return (u16)(u >> 16);
}

// ---------------- LayerNorm: fp32 in -> bf16 out, one block per row (D=1024) --
__global__ __launch_bounds__(256) void ln_kernel(
    const float* __restrict__ x, const float* __restrict__ g,
    const float* __restrict__ be, u16* __restrict__ out)
{
    const int row = blockIdx.x;
    const int tid = threadIdx.x;
    const float4 v = ((const float4*)(x + (long)row * 1024))[tid];
    float s = v.x + v.y + v.z + v.w;
#pragma unroll
    for (int d = 32; d >= 1; d >>= 1) s += __shfl_xor(s, d);
    __shared__ float r1[4], r2[4];
    if ((tid & 63) == 0) r1[tid >> 6] = s;
    __syncthreads();
    const float mean = (r1[0] + r1[1] + r1[2] + r1[3]) * (1.0f / 1024.0f);
    const float dx = v.x - mean, dy = v.y - mean, dz = v.z - mean, dw = v.w - mean;
    float sq = dx * dx + dy * dy + dz * dz + dw * dw;
#pragma unroll
    for (int d = 32; d >= 1; d >>= 1) sq += __shfl_xor(sq, d);
    if ((tid & 63) == 0) r2[tid >> 6] = sq;
    __syncthreads();
    const float var = (r2[0] + r2[1] + r2[2] + r2[3]) * (1.0f / 1024.0f);
    const float rstd = rsqrtf(var + 1e-5f);
    const float4 gg = ((const float4*)g)[tid];
    const float4 bb = ((const float4*)be)[tid];
    ushort4 o;
    o.x = f2bf(dx * rstd * gg.x + bb.x);
    o.y = f2bf(dy * rstd * gg.y + bb.y);
    o.z = f2bf(dz * rstd * gg.z + bb.z);
    o.w = f2bf(dw * rstd * gg.w + bb.w);
    *(ushort4*)&out[(long)row * 1024 + tid * 4] = o;
}

// ---------------- Transpose + cvt: fp32 [R][C] -> bf16 [C][R] ----------------
__global__ __launch_bounds__(256) void tcvt_kernel(
    const float* __restrict__ in, u16* __restrict__ outT, int R, int C)
{
    __shared__ float tile[32][33];
    const int tx = threadIdx.x, ty = threadIdx.y; // 32 x 8
    const int c0 = blockIdx.x * 32, r0 = blockIdx.y * 32;
#pragma unroll
    for (int i = 0; i < 4; ++i)
        tile[ty + i * 8][tx] = in[(long)(r0 + ty + i * 8) * C + c0 + tx];
    __syncthreads();
#pragma unroll
    for (int i = 0; i < 4; ++i)
        outT[(long)(c0 + ty + i * 8) * R + r0 + tx] = f2bf(tile[tx][ty + i * 8]);
}

// ---------------- GEMM body: C[M,N] = A[M,K] @ Bt[N,K]^T + bias --------------
// Depth-DP single-barrier pipeline: DP LDS buffers; per iter
//   vmcnt((DP-2)*LPW) -> s_barrier -> stage(t+DP-1) -> ds_read+MFMA.
// Stage-after-barrier targets buf[(t+DP-1)%DP] == buf[(t-1)%DP], whose readers
// all passed the barrier (they finished iter t-1) -> race-free with 1 barrier.
// Counted vmcnt keeps (DP-2) iterations of loads in flight (T3/T4).
// XCD swizzle (T1): contiguous work chunk per XCD for B-panel L2 residency.
// EPI 0: bf16. EPI 1: sigmoid-GELU -> bf16. EPI 2: += fp32 resid -> fp32.
// EPI 3: bf16, cols<1024 scaled by 0.125 (q-prescale folded into qkv GEMM).
template <int BM, int EPI, int DP>
static __device__ __forceinline__ void gemm_body(
    const u16* __restrict__ A, const u16* __restrict__ Bt,
    const float* __restrict__ bias, const float* __restrict__ resid,
    void* __restrict__ C, int M, int N, int K)
{
    constexpr int WN = (BM == 128) ? 2 : 4;   // waves along N
    constexpr int MR = 4;                     // m-frags per wave
    constexpr int NR = 128 / WN / 16;         // n-frags per wave (4 or 2)
    constexpr int AI = BM / 64;               // A stage instrs per wave
    constexpr int LPW = AI + 2;               // loads/wave/tile (A + B)
    __shared__ __align__(16) u16 As[DP][BM * 32];
    __shared__ __align__(16) u16 Bs[DP][128 * 32];
    const int tid = threadIdx.x;
    const int lane = tid & 63;
    const int w = tid >> 6;
    const int wm = w / WN, wn = w % WN;
    // XCD-aware bijective swizzle (nwg % 8 == 0 for all our grids)
    const int nwg = gridDim.x * gridDim.y;
    const int flat = blockIdx.x + gridDim.x * blockIdx.y;
    const int work = (flat & 7) * (nwg >> 3) + (flat >> 3);
    const int bm = work % gridDim.x, bn = work / gridDim.x;
    f32x4 acc[MR][NR] = {};

    const u16* Ablk = A + (long)bm * BM * K;
    const u16* Bblk = Bt + (long)bn * 128 * K;
    const int nt = K >> 5;

    auto stage = [&](int buf, int kb) {
#pragma unroll
        for (int i = 0; i < AI; ++i) {
            const int o = (w * AI + i) * 512 + lane * 8;
            const int row = o >> 5, kk = o & 31;
            __builtin_amdgcn_global_load_lds(
                (const __attribute__((address_space(1))) void*)(Ablk + (long)row * K + kb + kk),
                (__attribute__((address_space(3))) void*)(&As[buf][(w * AI + i) * 512]),
                16, 0, 0);
        }
#pragma unroll
        for (int i = 0; i < 2; ++i) {
            const int o = (w * 2 + i) * 512 + lane * 8;
            const int row = o >> 5, kk = o & 31;
            __builtin_amdgcn_global_load_lds(
                (const __attribute__((address_space(1))) void*)(Bblk + (long)row * K + kb + kk),
                (__attribute__((address_space(3))) void*)(&Bs[buf][(w * 2 + i) * 512]),
                16, 0, 0);
        }
    };

#pragma unroll
    for (int s = 0; s < DP - 1; ++s) stage(s, s << 5);   // prologue (nt >= 32)

    for (int t = 0; t < nt; ++t) {
        const int cur = t % DP;
        if (t + DP - 2 < nt) {
            asm volatile("s_waitcnt vmcnt(%0)" :: "i"((DP - 2) * LPW) : "memory");
        } else if (t + 1 < nt) {                          // reachable only DP>=4
            asm volatile("s_waitcnt vmcnt(%0)" :: "i"(LPW) : "memory");
        } else {
            asm volatile("s_waitcnt vmcnt(0)" ::: "memory");
        }
        __builtin_amdgcn_s_barrier();          // everyone's buf[cur] staged
        asm volatile("" ::: "memory");         // no LDS ops cross the barrier

        if (t + DP - 1 < nt) stage((t + DP - 1) % DP, (t + DP - 1) << 5);

        bf16x8 af[MR], bfr[NR];
#pragma unroll
        for (int m = 0; m < MR; ++m)
            af[m] = *(const bf16x8*)&As[cur][(wm * MR * 16 + m * 16 + (lane & 15)) * 32 + (lane >> 4) * 8];
#pragma unroll
        for (int n = 0; n < NR; ++n)
            bfr[n] = *(const bf16x8*)&Bs[cur][(wn * NR * 16 + n * 16 + (lane & 15)) * 32 + (lane >> 4) * 8];
#pragma unroll
        for (int m = 0; m < MR; ++m)
#pragma unroll
            for (int n = 0; n < NR; ++n)
                acc[m][n] = __builtin_amdgcn_mfma_f32_16x16x32_bf16(af[m], bfr[n], acc[m][n], 0, 0, 0);
        asm volatile("" ::: "memory");
    }

    const int rowBase = bm * BM + wm * MR * 16;
    const int colBase = bn * 128 + wn * NR * 16;
#pragma unroll
    for (int n = 0; n < NR; ++n) {
        const int col = colBase + n * 16 + (lane & 15);
        const float bv = bias[col];
#pragma unroll
        for (int m = 0; m < MR; ++m) {
#pragma unroll
            for (int r = 0; r < 4; ++r) {
                const int row = rowBase + m * 16 + (lane >> 4) * 4 + r;
                float v = acc[m][n][r] + bv;
                if constexpr (EPI == 1) {
                    // sigmoid-form GELU (|err| vs erf-GELU ~1e-3 << bf16 noise)
                    const float u = v + 0.044715f * v * v * v;
                    v = v / (1.0f + __expf(-1.5957691216057308f * u));
                }
                if constexpr (EPI == 3) {
                    if (col < 1024) v *= 0.125f;   // q-prescale (exact)
                }
                if constexpr (EPI == 2) {
                    ((float*)C)[(long)row * N + col] = v + resid[(long)row * N + col];
                } else {
                    ((u16*)C)[(long)row * N + col] = f2bf(v);
                }
            }
        }
    }
}

__global__ __launch_bounds__(256) void gemm_qkv(
    const u16* A, const u16* Bt, const float* bias, const float* resid,
    void* C, int M, int N, int K) { gemm_body<128, 3, 3>(A, Bt, bias, resid, C, M, N, K); }
__global__ __launch_bounds__(256) void gemm_fc(
    const u16* A, const u16* Bt, const float* bias, const float* resid,
    void* C, int M, int N, int K) { gemm_body<128, 1, 3>(A, Bt, bias, resid, C, M, N, K); }
__global__ __launch_bounds__(256) void gemm_ap(
    const u16* A, const u16* Bt, const float* bias, const float* resid,
    void* C, int M, int N, int K) { gemm_body<64, 2, 4>(A, Bt, bias, resid, C, M, N, K); }
__global__ __launch_bounds__(256) void gemm_fp(
    const u16* A, const u16* Bt, const float* bias, const float* resid,
    void* C, int M, int N, int K) { gemm_body<64, 2, 4>(A, Bt, bias, resid, C, M, N, K); }

// ---------------- Flash attention v5 (causal): swapped QK^T + lane-local SM --
// qkv: bf16 [B*S][3072] (q already prescaled by 0.125 in gemm_qkv).
// S^T = mfma(K, Q): lane holds S[q = lane&15][kv = f*16 + (lane>>4)*4 + r]
// -> lane-local softmax, defer-max (THR=8), packed b64 P-stores.
// XCD swizzle co-locates same-(b,h) blocks per XCD (K/V L2 residency).
__global__ __launch_bounds__(256) void attn_kernel(
    const u16* __restrict__ qkv, u16* __restrict__ outb)
{
    const int S = 2048;
    const int flat = blockIdx.x + 16 * blockIdx.y;   // nwg = 512
    const int work = (flat & 7) * 64 + (flat >> 3);
    const int ipair = work & 15;         // 0..15
    const int bh = work >> 4;            // b*16 + h
    const int b = bh >> 4, h = bh & 15;
    const int tid = threadIdx.x, lane = tid & 63, w = tid >> 6;
    __shared__ __align__(16) u16 Ks[2][64 * 72];     // [kv][hd], +8 pad
    __shared__ __align__(16) u16 Vs[2][64 * 72];     // [hd][kv^swz], +8 pad
    __shared__ __align__(16) u16 Ps[4][16 * 72];     // per-wave P [q][kv], +8 pad

    const long base = (long)b * S * 3072;
    const int rstage = tid >> 3;         // 0..31 (staging row within half-tile)
    const int cg = (tid & 7) * 8;        // staging col group
    const int sw = cg;                   // V swizzle bits
    const u16* kbase = qkv + base + 1024 + h * 64 + cg;
    const u16* vbase = qkv + base + 2048 + h * 64 + cg;

    for (int half = 0; half < 2; ++half) {
        const int qt = half ? 31 - ipair : ipair;
        const int q0 = qt * 64;

        bf16x8 qf[2];
        {
            const int qrow = q0 + w * 16 + (lane & 15);
#pragma unroll
            for (int c = 0; c < 2; ++c)
                qf[c] = *(const bf16x8*)&qkv[base + (long)qrow * 3072 + h * 64 + c * 32 + (lane >> 4) * 8];
        }

        f32x4 Of[4] = {};
        float m = -1e30f, l = 0.0f;      // scalar state for q-row (lane&15)

        ushort8 kr[2], vr[2];
#pragma unroll
        for (int it = 0; it < 2; ++it) {
            const long ro = (long)(it * 32 + rstage) * 3072;
            kr[it] = *(const ushort8*)&kbase[ro];
            vr[it] = *(const ushort8*)&vbase[ro];
        }
        __syncthreads();   // protect buffers from previous half's readers
#pragma unroll
        for (int it = 0; it < 2; ++it) {
            const int r = it * 32 + rstage;
            *(ushort8*)&Ks[0][r * 72 + cg] = kr[it];
#pragma unroll
            for (int j = 0; j < 8; ++j)
                Vs[0][(cg + j) * 72 + (r ^ sw)] = vr[it][j];
        }

        for (int kt = 0; kt <= qt; ++kt) {
            const int cur = kt & 1;
            if (kt < qt) {
#pragma unroll
                for (int it = 0; it < 2; ++it) {
                    const long ro = (long)((kt + 1) * 64 + it * 32 + rstage) * 3072;
                    kr[it] = *(const ushort8*)&kbase[ro];
                    vr[it] = *(const ushort8*)&vbase[ro];
                }
            }
            __syncthreads();   // buf[cur] staged & visible to all waves

            // S^T = K @ Q^T  (swapped): row = kv, col = q
            f32x4 Sf[4] = {};
#pragma unroll
            for (int f = 0; f < 4; ++f) {
#pragma unroll
                for (int c = 0; c < 2; ++c) {
                    const bf16x8 kf = *(const bf16x8*)&Ks[cur][(f * 16 + (lane & 15)) * 72 + c * 32 + (lane >> 4) * 8];
                    Sf[f] = __builtin_amdgcn_mfma_f32_16x16x32_bf16(kf, qf[c], Sf[f], 0, 0, 0);
                }
            }
            // causal mask (diagonal tile only): kv_local > q_local
            if (kt == qt) {
                const int ql = w * 16 + (lane & 15);
#pragma unroll
                for (int f = 0; f < 4; ++f) {
#pragma unroll
                    for (int r = 0; r < 4; ++r) {
                        const int kvl = f * 16 + ((lane >> 4) << 2) + r;
                        if (kvl > ql) Sf[f][r] = -1e30f;
                    }
                }
            }
            // lane-local online softmax with defer-max
            float pmax = Sf[0][0];
#pragma unroll
            for (int f = 0; f < 4; ++f)
#pragma unroll
                for (int r = 0; r < 4; ++r) pmax = fmaxf(pmax, Sf[f][r]);
            if (!__all(pmax <= m + 8.0f)) {
                float pm = pmax;
                pm = fmaxf(pm, __shfl_xor(pm, 16));
                pm = fmaxf(pm, __shfl_xor(pm, 32));
                const float mnew = fmaxf(m, pm);
                const float sc = __expf(m - mnew);
                m = mnew;
                l *= sc;
                float sco[4];
#pragma unroll
                for (int r = 0; r < 4; ++r)
                    sco[r] = __shfl(sc, ((lane >> 4) << 2) + r);
#pragma unroll
                for (int f = 0; f < 4; ++f)
#pragma unroll
                    for (int r = 0; r < 4; ++r) Of[f][r] *= sco[r];
            }
            float osum = 0.0f;
#pragma unroll
            for (int f = 0; f < 4; ++f)
#pragma unroll
                for (int r = 0; r < 4; ++r) {
                    const float e = __expf(Sf[f][r] - m);
                    Sf[f][r] = e;
                    osum += e;
                }
            l += osum;
            // P -> LDS: pack 4 consecutive kv (r=0..3) into one b64 write
#pragma unroll
            for (int f = 0; f < 4; ++f) {
                const unsigned lo = (unsigned)f2bf(Sf[f][0]) | ((unsigned)f2bf(Sf[f][1]) << 16);
                const unsigned hi = (unsigned)f2bf(Sf[f][2]) | ((unsigned)f2bf(Sf[f][3]) << 16);
                uint2 pk; pk.x = lo; pk.y = hi;
                *(uint2*)&Ps[w][(lane & 15) * 72 + f * 16 + ((lane >> 4) << 2)] = pk;
            }
            // O += P @ V
#pragma unroll
            for (int f = 0; f < 4; ++f) {
                const int hd = f * 16 + (lane & 15);
#pragma unroll
                for (int c = 0; c < 2; ++c) {
                    const int k0 = c * 32 + (lane >> 4) * 8;
                    const bf16x8 pa = *(const bf16x8*)&Ps[w][(lane & 15) * 72 + k0];
                    const bf16x8 vb = *(const bf16x8*)&Vs[cur][hd * 72 + (k0 ^ (hd & 56))];
                    Of[f] = __builtin_amdgcn_mfma_f32_16x16x32_bf16(pa, vb, Of[f], 0, 0, 0);
                }
            }
            if (kt < qt) {
#pragma unroll
                for (int it = 0; it < 2; ++it) {
                    const int r = it * 32 + rstage;
                    *(ushort8*)&Ks[cur ^ 1][r * 72 + cg] = kr[it];
#pragma unroll
                    for (int j = 0; j < 8; ++j)
                        Vs[cur ^ 1][(cg + j) * 72 + (r ^ sw)] = vr[it][j];
                }
            }
        }

        // reduce l across the 4 kv-copies of each q-row, broadcast to O rows
        float lt = l;
        lt += __shfl_xor(lt, 16);
        lt += __shfl_xor(lt, 32);
        const float linv = 1.0f / lt;
        float inv[4];
#pragma unroll
        for (int r = 0; r < 4; ++r)
            inv[r] = __shfl(linv, ((lane >> 4) << 2) + r);
#pragma unroll
        for (int f = 0; f < 4; ++f) {
            const int col = h * 64 + f * 16 + (lane & 15);
#pragma unroll
            for (int r = 0; r < 4; ++r) {
                const int qrow = q0 + w * 16 + (lane >> 4) * 4 + r;
                outb[((long)b * S + qrow) * 1024 + col] = f2bf(Of[f][r] * inv[r]);
            }
        }
    }
}

// -----------------------------------------------------------------------------
// Workspace plan (56 MiB total; x1 lives in d_out):
//   [0        , 6291456 )  wTa   bf16 [3072][1024]   (dead after qkv GEMM)
//   [6291456  , 8388608 )  wTap  bf16 [1024][1024]   (dead after attn-proj)
//   [8388608  , 16777216)  wTfc  bf16 [4096][1024]
//   [16777216 , 25165824)  wTfp  bf16 [1024][4096]
//   [25165824 , 33554432)  hao   bf16 [4096][1024]   h (ln1 out), then ao (attn out)
//   [33554432 , 58720256)  qkv   bf16 [4096][3072]
//   mb = [25165824, 58720256) bf16 [4096][4096]      (over hao∪qkv, both dead)
//   h2 = [0, 8388608)       bf16 [4096][1024]        (over wTa∪wTap, both dead)
extern "C" void kernel_launch(void* const* d_in, const int* in_sizes, int n_in,
                              void* d_out, int out_size, void* d_ws, size_t ws_size,
                              hipStream_t stream) {
    const float* x      = (const float*)d_in[0];
    const float* ln1_g  = (const float*)d_in[1];
    const float* ln1_b  = (const float*)d_in[2];
    const float* w_attn = (const float*)d_in[3];
    const float* b_attn = (const float*)d_in[4];
    const float* w_ap   = (const float*)d_in[5];
    const float* b_ap   = (const float*)d_in[6];
    const float* ln2_g  = (const float*)d_in[7];
    const float* ln2_b  = (const float*)d_in[8];
    const float* w_fc   = (const float*)d_in[9];
    const float* b_fc   = (const float*)d_in[10];
    const float* w_fp   = (const float*)d_in[11];
    const float* b_fp   = (const float*)d_in[12];
    float* out = (float*)d_out;

    const int R = 4096; // B*S
    char* p = (char*)d_ws;
    u16*   wTa  = (u16*)(p);
    u16*   wTap = (u16*)(p + 6291456);
    u16*   wTfc = (u16*)(p + 8388608);
    u16*   wTfp = (u16*)(p + 16777216);
    u16*   hao  = (u16*)(p + 25165824);   // h, later reused as ao
    u16*   qkv  = (u16*)(p + 33554432);
    u16*   mb   = hao;                    // spans hao + qkv (33,554,432 B)
    u16*   h2   = wTa;                    // spans wTa + wTap (8,388,608 B)
    float* x1   = out;                    // residual stream lives in d_out

    const dim3 tb(32, 8);
    tcvt_kernel<<<dim3(3072 / 32, 1024 / 32), tb, 0, stream>>>(w_attn, wTa, 1024, 3072);
    tcvt_kernel<<<dim3(1024 / 32, 1024 / 32), tb, 0, stream>>>(w_ap, wTap, 1024, 1024);
    tcvt_kernel<<<dim3(4096 / 32, 1024 / 32), tb, 0, stream>>>(w_fc, wTfc, 1024, 4096);
    tcvt_kernel<<<dim3(1024 / 32, 4096 / 32), tb, 0, stream>>>(w_fp, wTfp, 4096, 1024);

    ln_kernel<<<R, 256, 0, stream>>>(x, ln1_g, ln1_b, hao);
    gemm_qkv<<<dim3(32, 24), 256, 0, stream>>>(hao, wTa, b_attn, nullptr, qkv, R, 3072, 1024);
    attn_kernel<<<dim3(16, 32), 256, 0, stream>>>(qkv, hao);
    gemm_ap<<<dim3(64, 8), 256, 0, stream>>>(hao, wTap, b_ap, x, x1, R, 1024, 1024);
    ln_kernel<<<R, 256, 0, stream>>>(x1, ln2_g, ln2_b, h2);
    gemm_fc<<<dim3(32, 32), 256, 0, stream>>>(h2, wTfc, b_fc, nullptr, mb, R, 4096, 1024);
    gemm_fp<<<dim3(64, 8), 256, 0, stream>>>(mb, wTfp, b_fp, x1, out, R, 1024, 4096);
}